// Round 2
// baseline (326.803 us; speedup 1.0000x reference)
//
#include <hip/hip_runtime.h>
#include <hip/hip_bf16.h>
#include <math.h>

#define BATCH  2
#define LSEQ   2048
#define FEAT   2048
#define DINNER 2048
#define DSTATE 16
#define DTRANK 128
#define NDBC   160            // DT_RANK + 2*D_STATE
#define NCHUNK 64
#define LCHUNK (LSEQ / NCHUNK) // 32
#define BL     (BATCH * LSEQ)  // 4096

typedef __attribute__((ext_vector_type(8))) short bf16x8;
typedef __attribute__((ext_vector_type(4))) float floatx4;

#if __has_builtin(__builtin_amdgcn_exp2f)
#define EXP2F(x) __builtin_amdgcn_exp2f(x)
#else
#define EXP2F(x) exp2f(x)
#endif

// ---------------- split fp32 -> bf16 hi + bf16 lo (8 elems/thread) ----------------
__global__ __launch_bounds__(256) void split_bf16(const float* __restrict__ src,
                                                  __hip_bfloat16* __restrict__ hi,
                                                  __hip_bfloat16* __restrict__ lo,
                                                  int n8) {
    int t = blockIdx.x * 256 + threadIdx.x;
    if (t >= n8) return;
    const floatx4* s4 = (const floatx4*)(src) + t * 2;
    floatx4 v0 = s4[0], v1 = s4[1];
    union { bf16x8 v; __hip_bfloat16 b[8]; } H, L;
#pragma unroll
    for (int i = 0; i < 4; ++i) {
        float v = v0[i];
        __hip_bfloat16 h = __float2bfloat16(v);
        H.b[i] = h; L.b[i] = __float2bfloat16(v - __bfloat162float(h));
    }
#pragma unroll
    for (int i = 0; i < 4; ++i) {
        float v = v1[i];
        __hip_bfloat16 h = __float2bfloat16(v);
        H.b[4 + i] = h; L.b[4 + i] = __float2bfloat16(v - __bfloat162float(h));
    }
    ((bf16x8*)hi)[t] = H.v;
    ((bf16x8*)lo)[t] = L.v;
}

// ---------------- A2T[s][d] = -exp(A_log[d][s]) * log2(e) ----------------
__global__ __launch_bounds__(256) void prep_a2(const float* __restrict__ Alog,
                                               float* __restrict__ A2T) {
    int tid = blockIdx.x * 256 + threadIdx.x;   // 32768 threads
    int s = tid >> 11;
    int d = tid & (DINNER - 1);
    A2T[s * DINNER + d] = -__expf(Alog[d * DSTATE + s]) * 1.4426950408889634f;
}

// ---------------- GEMM1: deltaBC = x @ W_dbc^T + b_dbc (split-bf16 MFMA) --------
// emits dbc fp32, plus hi/lo bf16 split of delta_lo (first 128 cols) for GEMM2
__global__ __launch_bounds__(64) void gemm_dbc(
    const __hip_bfloat16* __restrict__ xh, const __hip_bfloat16* __restrict__ xl,
    const __hip_bfloat16* __restrict__ wh, const __hip_bfloat16* __restrict__ wl,
    const float* __restrict__ bdbc,
    float* __restrict__ dbc, __hip_bfloat16* __restrict__ dhi, __hip_bfloat16* __restrict__ dlo)
{
    int mt = blockIdx.x, nt = blockIdx.y;
    int lane = threadIdx.x;
    int lm = lane & 15, quad = lane >> 4;
    size_t aoff = (size_t)(mt * 16 + lm) * FEAT + quad * 8;
    size_t boff = (size_t)(nt * 16 + lm) * FEAT + quad * 8;
    floatx4 acc = {0.f, 0.f, 0.f, 0.f};
    for (int k = 0; k < FEAT; k += 32) {
        bf16x8 ah = *(const bf16x8*)(xh + aoff + k);
        bf16x8 al = *(const bf16x8*)(xl + aoff + k);
        bf16x8 bh = *(const bf16x8*)(wh + boff + k);
        bf16x8 bl = *(const bf16x8*)(wl + boff + k);
        acc = __builtin_amdgcn_mfma_f32_16x16x32_bf16(ah, bh, acc, 0, 0, 0);
        acc = __builtin_amdgcn_mfma_f32_16x16x32_bf16(ah, bl, acc, 0, 0, 0);
        acc = __builtin_amdgcn_mfma_f32_16x16x32_bf16(al, bh, acc, 0, 0, 0);
    }
    int n = nt * 16 + lm;
    float bias = bdbc[n];
#pragma unroll
    for (int i = 0; i < 4; ++i) {
        int m = mt * 16 + quad * 4 + i;
        float v = acc[i] + bias;
        dbc[(size_t)m * NDBC + n] = v;
        if (nt < 8) {  // block-uniform branch
            __hip_bfloat16 h = __float2bfloat16(v);
            dhi[(size_t)m * DTRANK + n] = h;
            dlo[(size_t)m * DTRANK + n] = __float2bfloat16(v - __bfloat162float(h));
        }
    }
}

// ---------------- GEMM2: delta = softplus(delta_lo @ W_dt^T + b_dt) -------------
__global__ __launch_bounds__(64) void gemm_dt(
    const __hip_bfloat16* __restrict__ dhi, const __hip_bfloat16* __restrict__ dlo,
    const __hip_bfloat16* __restrict__ wh, const __hip_bfloat16* __restrict__ wl,
    const float* __restrict__ bdt,
    float* __restrict__ delta)
{
    int mt = blockIdx.x, nt = blockIdx.y;
    int lane = threadIdx.x;
    int lm = lane & 15, quad = lane >> 4;
    size_t aoff = (size_t)(mt * 16 + lm) * DTRANK + quad * 8;
    size_t boff = (size_t)(nt * 16 + lm) * DTRANK + quad * 8;
    floatx4 acc = {0.f, 0.f, 0.f, 0.f};
#pragma unroll
    for (int k = 0; k < DTRANK; k += 32) {
        bf16x8 ah = *(const bf16x8*)(dhi + aoff + k);
        bf16x8 al = *(const bf16x8*)(dlo + aoff + k);
        bf16x8 bh = *(const bf16x8*)(wh + boff + k);
        bf16x8 bl = *(const bf16x8*)(wl + boff + k);
        acc = __builtin_amdgcn_mfma_f32_16x16x32_bf16(ah, bh, acc, 0, 0, 0);
        acc = __builtin_amdgcn_mfma_f32_16x16x32_bf16(ah, bl, acc, 0, 0, 0);
        acc = __builtin_amdgcn_mfma_f32_16x16x32_bf16(al, bh, acc, 0, 0, 0);
    }
    int n = nt * 16 + lm;
    float bias = bdt[n];
#pragma unroll
    for (int i = 0; i < 4; ++i) {
        int m = mt * 16 + quad * 4 + i;
        float v = acc[i] + bias;
        float sp = fmaxf(v, 0.f) + log1pf(__expf(-fabsf(v)));  // stable softplus
        delta[(size_t)m * DINNER + n] = sp;
    }
}

// ---------------- Pass A: chunk-local scan from h=0; record h_end and sum(delta) ----
__global__ __launch_bounds__(256) void scan_partial(
    const float* __restrict__ delta, const float* __restrict__ x,
    const float* __restrict__ dbc, const float* __restrict__ A2T,
    float* __restrict__ hA, float* __restrict__ sumd)
{
    int tid = blockIdx.x * 256 + threadIdx.x;  // 262144
    int d = tid & (DINNER - 1);
    int c = (tid >> 11) & (NCHUNK - 1);
    int b = tid >> 17;
    float a2[DSTATE], h[DSTATE];
#pragma unroll
    for (int s = 0; s < DSTATE; ++s) { a2[s] = A2T[s * DINNER + d]; h[s] = 0.f; }
    float sd = 0.f;
    int l0 = c * LCHUNK;
    for (int i = 0; i < LCHUNK; ++i) {
        int bl = b * LSEQ + l0 + i;
        float dl = delta[(size_t)bl * DINNER + d];
        float xv = x[(size_t)bl * DINNER + d];
        const floatx4* Bp = (const floatx4*)(dbc + (size_t)bl * NDBC + DTRANK);
        float du = dl * xv;
        sd += dl;
#pragma unroll
        for (int q = 0; q < 4; ++q) {
            floatx4 Bq = Bp[q];
#pragma unroll
            for (int j = 0; j < 4; ++j) {
                int s = q * 4 + j;
                float dA = EXP2F(dl * a2[s]);
                h[s] = fmaf(dA, h[s], du * Bq[j]);
            }
        }
    }
    size_t idx = (size_t)(b * NCHUNK + c) * DINNER + d;
    floatx4* o4 = (floatx4*)(hA + idx * DSTATE);
#pragma unroll
    for (int q = 0; q < 4; ++q) {
        floatx4 v = {h[q * 4], h[q * 4 + 1], h[q * 4 + 2], h[q * 4 + 3]};
        o4[q] = v;
    }
    sumd[idx] = sd;
}

// ---------------- Pass B: exclusive combine across chunks (in-place hA -> h_in) ----
__global__ __launch_bounds__(256) void scan_combine(
    float* __restrict__ hA, const float* __restrict__ sumd, const float* __restrict__ A2T)
{
    int tid = blockIdx.x * 256 + threadIdx.x;  // 65536
    int s = tid & 15;
    int d = (tid >> 4) & (DINNER - 1);
    int b = tid >> 15;
    float a2s = A2T[s * DINNER + d];
    float hin = 0.f;
    for (int c = 0; c < NCHUNK; ++c) {
        size_t idx = (size_t)(b * NCHUNK + c) * DINNER + d;
        float sdv = sumd[idx];
        size_t off = idx * DSTATE + s;
        float hAv = hA[off];
        hA[off] = hin;                       // h_in for chunk c
        hin = EXP2F(a2s * sdv) * hin + hAv;  // state after chunk c
    }
}

// ---------------- Pass C: re-scan chunks from h_in, emit y ----------------
__global__ __launch_bounds__(256) void scan_final(
    const float* __restrict__ delta, const float* __restrict__ x,
    const float* __restrict__ dbc, const float* __restrict__ A2T,
    const float* __restrict__ hin, const float* __restrict__ Dp,
    float* __restrict__ out)
{
    int tid = blockIdx.x * 256 + threadIdx.x;  // 262144
    int d = tid & (DINNER - 1);
    int c = (tid >> 11) & (NCHUNK - 1);
    int b = tid >> 17;
    float a2[DSTATE], h[DSTATE];
    size_t idx = (size_t)(b * NCHUNK + c) * DINNER + d;
    const floatx4* i4 = (const floatx4*)(hin + idx * DSTATE);
#pragma unroll
    for (int q = 0; q < 4; ++q) {
        floatx4 v = i4[q];
#pragma unroll
        for (int j = 0; j < 4; ++j) h[q * 4 + j] = v[j];
    }
#pragma unroll
    for (int s = 0; s < DSTATE; ++s) a2[s] = A2T[s * DINNER + d];
    float Dd = Dp[d];
    int l0 = c * LCHUNK;
    for (int i = 0; i < LCHUNK; ++i) {
        int bl = b * LSEQ + l0 + i;
        float dl = delta[(size_t)bl * DINNER + d];
        float xv = x[(size_t)bl * DINNER + d];
        const floatx4* Bp = (const floatx4*)(dbc + (size_t)bl * NDBC + DTRANK);
        const floatx4* Cp = (const floatx4*)(dbc + (size_t)bl * NDBC + DTRANK + DSTATE);
        float du = dl * xv;
        float y = 0.f;
#pragma unroll
        for (int q = 0; q < 4; ++q) {
            floatx4 Bq = Bp[q];
            floatx4 Cq = Cp[q];
#pragma unroll
            for (int j = 0; j < 4; ++j) {
                int s = q * 4 + j;
                float dA = EXP2F(dl * a2[s]);
                h[s] = fmaf(dA, h[s], du * Bq[j]);
                y = fmaf(h[s], Cq[j], y);
            }
        }
        out[(size_t)bl * DINNER + d] = fmaf(Dd, xv, y);
    }
}

extern "C" void kernel_launch(void* const* d_in, const int* in_sizes, int n_in,
                              void* d_out, int out_size, void* d_ws, size_t ws_size,
                              hipStream_t stream) {
    const float* x    = (const float*)d_in[0];
    const float* Wdbc = (const float*)d_in[1];
    const float* bdbc = (const float*)d_in[2];
    const float* Wdt  = (const float*)d_in[3];
    const float* bdt  = (const float*)d_in[4];
    const float* Alog = (const float*)d_in[5];
    const float* Dp   = (const float*)d_in[6];
    float* out = (float*)d_out;

    char* w = (char*)d_ws;
    float* dbc = (float*)w;                      w += (size_t)BL * NDBC * 4;       // 2.62 MB
    __hip_bfloat16* dhi = (__hip_bfloat16*)w;    w += (size_t)BL * DTRANK * 2;     // 1.05 MB
    __hip_bfloat16* dlo = (__hip_bfloat16*)w;    w += (size_t)BL * DTRANK * 2;     // 1.05 MB
    float* delta = (float*)w;                    w += (size_t)BL * DINNER * 4;     // 33.6 MB
    float* A2T = (float*)w;                      w += (size_t)DSTATE * DINNER * 4; // 0.13 MB
    float* hA = (float*)w;                       w += (size_t)BATCH * NCHUNK * DINNER * DSTATE * 4; // 16.8 MB
    float* sumd = (float*)w;                     w += (size_t)BATCH * NCHUNK * DINNER * 4;          // 1.05 MB
    __hip_bfloat16* xh = (__hip_bfloat16*)w;     w += (size_t)BL * FEAT * 2;       // 16.8 MB
    __hip_bfloat16* xl = (__hip_bfloat16*)w;     w += (size_t)BL * FEAT * 2;       // 16.8 MB
    __hip_bfloat16* wdbch = (__hip_bfloat16*)w;  w += (size_t)NDBC * FEAT * 2;     // 0.66 MB
    __hip_bfloat16* wdbcl = (__hip_bfloat16*)w;  w += (size_t)NDBC * FEAT * 2;     // 0.66 MB
    __hip_bfloat16* wdth = (__hip_bfloat16*)w;   w += (size_t)DINNER * DTRANK * 2; // 0.52 MB
    __hip_bfloat16* wdtl = (__hip_bfloat16*)w;   w += (size_t)DINNER * DTRANK * 2; // 0.52 MB

    int nx8 = BL * FEAT / 8;          // 1048576
    int nwdbc8 = NDBC * FEAT / 8;     // 40960
    int nwdt8 = DINNER * DTRANK / 8;  // 32768
    hipLaunchKernelGGL(split_bf16, dim3(nx8 / 256), dim3(256), 0, stream, x, xh, xl, nx8);
    hipLaunchKernelGGL(split_bf16, dim3(nwdbc8 / 256), dim3(256), 0, stream, Wdbc, wdbch, wdbcl, nwdbc8);
    hipLaunchKernelGGL(split_bf16, dim3(nwdt8 / 256), dim3(256), 0, stream, Wdt, wdth, wdtl, nwdt8);
    hipLaunchKernelGGL(prep_a2, dim3((DSTATE * DINNER) / 256), dim3(256), 0, stream, Alog, A2T);
    hipLaunchKernelGGL(gemm_dbc, dim3(BL / 16, NDBC / 16), dim3(64), 0, stream,
                       xh, xl, wdbch, wdbcl, bdbc, dbc, dhi, dlo);
    hipLaunchKernelGGL(gemm_dt, dim3(BL / 16, DINNER / 16), dim3(64), 0, stream,
                       dhi, dlo, wdth, wdtl, bdt, delta);
    hipLaunchKernelGGL(scan_partial, dim3((BATCH * NCHUNK * DINNER) / 256), dim3(256), 0, stream,
                       delta, x, dbc, A2T, hA, sumd);
    hipLaunchKernelGGL(scan_combine, dim3((BATCH * DINNER * DSTATE) / 256), dim3(256), 0, stream,
                       hA, sumd, A2T);
    hipLaunchKernelGGL(scan_final, dim3((BATCH * NCHUNK * DINNER) / 256), dim3(256), 0, stream,
                       delta, x, dbc, A2T, hA, Dp, out);
}

// Round 3
// 304.373 us; speedup vs baseline: 1.0737x; 1.0737x over previous
//
#include <hip/hip_runtime.h>
#include <hip/hip_bf16.h>
#include <math.h>

#define BATCH  2
#define LSEQ   2048
#define FEAT   2048
#define DINNER 2048
#define DSTATE 16
#define DTRANK 128
#define NDBC   160             // DT_RANK + 2*D_STATE
#define NCHUNK 32
#define LCHUNK (LSEQ / NCHUNK) // 64
#define BL     (BATCH * LSEQ)  // 4096
#define KSPLIT 8
#define KCH    (FEAT / KSPLIT) // 256
#define KSUB   64
#define BSTRIDE 72             // LDS row stride (bf16): 144 B = 9*16 B -> conflict-safe b128

typedef __attribute__((ext_vector_type(8))) short bf16x8;
typedef __attribute__((ext_vector_type(4))) short bf16x4;
typedef __attribute__((ext_vector_type(4))) float floatx4;

#if __has_builtin(__builtin_amdgcn_exp2f)
#define EXP2F(x) __builtin_amdgcn_exp2f(x)
#else
#define EXP2F(x) exp2f(x)
#endif

__device__ inline void split8(floatx4 a0, floatx4 a1, bf16x8* h, bf16x8* l) {
    union { bf16x8 v; __hip_bfloat16 e[8]; } H, L;
    float v[8] = {a0[0], a0[1], a0[2], a0[3], a1[0], a1[1], a1[2], a1[3]};
#pragma unroll
    for (int i = 0; i < 8; ++i) {
        H.e[i] = __float2bfloat16(v[i]);
        L.e[i] = __float2bfloat16(v[i] - __bfloat162float(H.e[i]));
    }
    *h = H.v; *l = L.v;
}

// ---------------- split fp32 -> bf16 hi + lo (weights only) ----------------
__global__ __launch_bounds__(256) void split_bf16(const float* __restrict__ src,
                                                  __hip_bfloat16* __restrict__ hi,
                                                  __hip_bfloat16* __restrict__ lo,
                                                  int n8) {
    int t = blockIdx.x * 256 + threadIdx.x;
    if (t >= n8) return;
    const floatx4* s4 = (const floatx4*)(src) + t * 2;
    bf16x8 h, l;
    split8(s4[0], s4[1], &h, &l);
    ((bf16x8*)hi)[t] = h;
    ((bf16x8*)lo)[t] = l;
}

// ---------------- A2T[s][d] = -exp(A_log[d][s]) * log2(e) ----------------
__global__ __launch_bounds__(256) void prep_a2(const float* __restrict__ Alog,
                                               float* __restrict__ A2T) {
    int tid = blockIdx.x * 256 + threadIdx.x;   // 32768
    int s = tid >> 11;
    int d = tid & (DINNER - 1);
    A2T[s * DINNER + d] = -__expf(Alog[d * DSTATE + s]) * 1.4426950408889634f;
}

// ---------------- GEMM1 split-K: partial[ks] = x(chunk) @ W_dbc(chunk)^T ----------------
// 256 thr = 4 waves, M-tile 64, all 160 N-cols, K-chunk 256 staged in LDS (W hi/lo),
// x read fp32 from global and hi/lo-split in-register.
__global__ __launch_bounds__(256) void gemm_dbc(
    const float* __restrict__ x,
    const __hip_bfloat16* __restrict__ wh, const __hip_bfloat16* __restrict__ wl,
    float* __restrict__ partial)
{
    __shared__ __hip_bfloat16 Bh[NDBC * BSTRIDE];
    __shared__ __hip_bfloat16 Bl[NDBC * BSTRIDE];
    int mt = blockIdx.x, ks = blockIdx.y;
    int t = threadIdx.x;
    int wave = t >> 6, lane = t & 63, lm = lane & 15, q = lane >> 4;
    int m0 = mt * 64;
    int k0 = ks * KCH;
    const float* xrow = x + (size_t)(m0 + wave * 16 + lm) * FEAT;
    floatx4 acc[10];
#pragma unroll
    for (int i = 0; i < 10; ++i) acc[i] = (floatx4){0.f, 0.f, 0.f, 0.f};
    int sr = t >> 3, scb = t & 7;
    for (int kc = 0; kc < KCH; kc += KSUB) {
        // stage 160x64 hi/lo W chunk
#pragma unroll
        for (int r = sr; r < NDBC; r += 32) {
            size_t g = (size_t)r * FEAT + k0 + kc + scb * 8;
            *(bf16x8*)&Bh[r * BSTRIDE + scb * 8] = *(const bf16x8*)&wh[g];
            *(bf16x8*)&Bl[r * BSTRIDE + scb * 8] = *(const bf16x8*)&wl[g];
        }
        __syncthreads();
#pragma unroll
        for (int kk = 0; kk < KSUB; kk += 32) {
            int col = k0 + kc + kk + q * 8;
            floatx4 a0 = *(const floatx4*)(xrow + col);
            floatx4 a1 = *(const floatx4*)(xrow + col + 4);
            bf16x8 ah, al;
            split8(a0, a1, &ah, &al);
#pragma unroll
            for (int nt = 0; nt < 10; ++nt) {
                int boff = (nt * 16 + lm) * BSTRIDE + kk + q * 8;
                bf16x8 bh = *(const bf16x8*)&Bh[boff];
                bf16x8 bl = *(const bf16x8*)&Bl[boff];
                acc[nt] = __builtin_amdgcn_mfma_f32_16x16x32_bf16(ah, bh, acc[nt], 0, 0, 0);
                acc[nt] = __builtin_amdgcn_mfma_f32_16x16x32_bf16(ah, bl, acc[nt], 0, 0, 0);
                acc[nt] = __builtin_amdgcn_mfma_f32_16x16x32_bf16(al, bh, acc[nt], 0, 0, 0);
            }
        }
        __syncthreads();
    }
    float* pout = partial + ((size_t)ks * BL + m0 + wave * 16 + q * 4) * NDBC;
#pragma unroll
    for (int nt = 0; nt < 10; ++nt)
#pragma unroll
        for (int i = 0; i < 4; ++i)
            pout[(size_t)i * NDBC + nt * 16 + lm] = acc[nt][i];
}

// ---------------- finalize: sum K-partials + bias -> dbcBC fp32 + delta_lo hi/lo ----------------
__global__ __launch_bounds__(256) void finalize_dbc(
    const float* __restrict__ partial, const float* __restrict__ bias,
    float* __restrict__ dbcBC, __hip_bfloat16* __restrict__ dhi, __hip_bfloat16* __restrict__ dlo)
{
    int tid = blockIdx.x * 256 + threadIdx.x;  // 163840
    int m = tid / 40, c4 = tid - m * 40;
    int n = c4 * 4;
    floatx4 s = *(const floatx4*)(bias + n);
#pragma unroll
    for (int ks = 0; ks < KSPLIT; ++ks) {
        floatx4 p = *(const floatx4*)(partial + ((size_t)ks * BL + m) * NDBC + n);
        s = s + p;
    }
    if (c4 < 32) {
        union { bf16x4 v; __hip_bfloat16 e[4]; } H, L;
#pragma unroll
        for (int i = 0; i < 4; ++i) {
            H.e[i] = __float2bfloat16(s[i]);
            L.e[i] = __float2bfloat16(s[i] - __bfloat162float(H.e[i]));
        }
        *(bf16x4*)(dhi + (size_t)m * DTRANK + n) = H.v;
        *(bf16x4*)(dlo + (size_t)m * DTRANK + n) = L.v;
    } else {
        *(floatx4*)(dbcBC + (size_t)m * 32 + (n - 128)) = s;
    }
}

// ---------------- GEMM2: delta = softplus(delta_lo @ W_dt^T + b_dt) ----------------
// 4 waves/block, 32 rows/wave (A K=128 held in regs), 4 N-tiles/block
__global__ __launch_bounds__(256) void gemm_dt(
    const __hip_bfloat16* __restrict__ dhi, const __hip_bfloat16* __restrict__ dlo,
    const __hip_bfloat16* __restrict__ wh, const __hip_bfloat16* __restrict__ wl,
    const float* __restrict__ bdt, float* __restrict__ delta)
{
    int mt = blockIdx.x, ntb = blockIdx.y;   // (32, 32)
    int t = threadIdx.x, wave = t >> 6, lane = t & 63, lm = lane & 15, q = lane >> 4;
    int m0 = mt * 128 + wave * 32;
    int n0 = ntb * 64;
    bf16x8 AH[2][4], AL[2][4];
#pragma unroll
    for (int sub = 0; sub < 2; ++sub) {
        const __hip_bfloat16* ah = dhi + (size_t)(m0 + sub * 16 + lm) * DTRANK + q * 8;
        const __hip_bfloat16* al = dlo + (size_t)(m0 + sub * 16 + lm) * DTRANK + q * 8;
#pragma unroll
        for (int kp = 0; kp < 4; ++kp) {
            AH[sub][kp] = *(const bf16x8*)(ah + kp * 32);
            AL[sub][kp] = *(const bf16x8*)(al + kp * 32);
        }
    }
    floatx4 acc[4][2];
#pragma unroll
    for (int i = 0; i < 4; ++i)
#pragma unroll
        for (int j = 0; j < 2; ++j) acc[i][j] = (floatx4){0.f, 0.f, 0.f, 0.f};
#pragma unroll
    for (int nt = 0; nt < 4; ++nt) {
        const __hip_bfloat16* bh = wh + (size_t)(n0 + nt * 16 + lm) * DTRANK + q * 8;
        const __hip_bfloat16* blp = wl + (size_t)(n0 + nt * 16 + lm) * DTRANK + q * 8;
#pragma unroll
        for (int kp = 0; kp < 4; ++kp) {
            bf16x8 bhv = *(const bf16x8*)(bh + kp * 32);
            bf16x8 blv = *(const bf16x8*)(blp + kp * 32);
#pragma unroll
            for (int sub = 0; sub < 2; ++sub) {
                acc[nt][sub] = __builtin_amdgcn_mfma_f32_16x16x32_bf16(AH[sub][kp], bhv, acc[nt][sub], 0, 0, 0);
                acc[nt][sub] = __builtin_amdgcn_mfma_f32_16x16x32_bf16(AH[sub][kp], blv, acc[nt][sub], 0, 0, 0);
                acc[nt][sub] = __builtin_amdgcn_mfma_f32_16x16x32_bf16(AL[sub][kp], bhv, acc[nt][sub], 0, 0, 0);
            }
        }
    }
#pragma unroll
    for (int nt = 0; nt < 4; ++nt) {
        int n = n0 + nt * 16 + lm;
        float bias = bdt[n];
#pragma unroll
        for (int sub = 0; sub < 2; ++sub)
#pragma unroll
            for (int i = 0; i < 4; ++i) {
                int m = m0 + sub * 16 + q * 4 + i;
                float v = acc[nt][sub][i] + bias;
                float sp = fmaxf(v, 0.f) + log1pf(__expf(-fabsf(v)));
                delta[(size_t)m * DINNER + n] = sp;
            }
    }
}

// ---------------- Pass A: chunk-local scan from h=0; record h_end and sum(delta) ----
__global__ __launch_bounds__(256) void scan_partial(
    const float* __restrict__ delta, const float* __restrict__ x,
    const float* __restrict__ dbcBC, const float* __restrict__ A2T,
    float* __restrict__ hA, float* __restrict__ sumd)
{
    int tid = blockIdx.x * 256 + threadIdx.x;  // 131072
    int d = tid & (DINNER - 1);
    int c = (tid >> 11) & (NCHUNK - 1);
    int b = tid >> 16;
    float a2[DSTATE], h[DSTATE];
#pragma unroll
    for (int s = 0; s < DSTATE; ++s) { a2[s] = A2T[s * DINNER + d]; h[s] = 0.f; }
    float sd = 0.f;
    int l0 = c * LCHUNK;
#pragma unroll 2
    for (int i = 0; i < LCHUNK; ++i) {
        int bl = b * LSEQ + l0 + i;
        float dl = delta[(size_t)bl * DINNER + d];
        float xv = x[(size_t)bl * DINNER + d];
        const floatx4* Bp = (const floatx4*)(dbcBC + (size_t)bl * 32);
        float du = dl * xv;
        sd += dl;
#pragma unroll
        for (int qq = 0; qq < 4; ++qq) {
            floatx4 Bq = Bp[qq];
#pragma unroll
            for (int j = 0; j < 4; ++j) {
                int s = qq * 4 + j;
                float dA = EXP2F(dl * a2[s]);
                h[s] = fmaf(dA, h[s], du * Bq[j]);
            }
        }
    }
    size_t idx = (size_t)(b * NCHUNK + c) * DINNER + d;
    floatx4* o4 = (floatx4*)(hA + idx * DSTATE);
#pragma unroll
    for (int qq = 0; qq < 4; ++qq) {
        floatx4 v = {h[qq * 4], h[qq * 4 + 1], h[qq * 4 + 2], h[qq * 4 + 3]};
        o4[qq] = v;
    }
    sumd[idx] = sd;
}

// ---------------- Pass B: exclusive combine across chunks (in-place hA -> h_in) ----
__global__ __launch_bounds__(256) void scan_combine(
    float* __restrict__ hA, const float* __restrict__ sumd, const float* __restrict__ A2T)
{
    int tid = blockIdx.x * 256 + threadIdx.x;  // 65536
    int s = tid & 15;
    int d = (tid >> 4) & (DINNER - 1);
    int b = tid >> 15;
    float a2s = A2T[s * DINNER + d];
    float hin = 0.f;
    size_t idx0 = (size_t)(b * NCHUNK) * DINNER + d;
    float sd_c = sumd[idx0];
    float hA_c = hA[idx0 * DSTATE + s];
    for (int c = 0; c < NCHUNK; ++c) {
        size_t idx = (size_t)(b * NCHUNK + c) * DINNER + d;
        float sd_n = 0.f, hA_n = 0.f;
        if (c + 1 < NCHUNK) {
            size_t idxn = idx + DINNER;
            sd_n = sumd[idxn];
            hA_n = hA[idxn * DSTATE + s];
        }
        hA[idx * DSTATE + s] = hin;
        hin = EXP2F(a2s * sd_c) * hin + hA_c;
        sd_c = sd_n; hA_c = hA_n;
    }
}

// ---------------- Pass C: re-scan chunks from h_in, emit y ----------------
__global__ __launch_bounds__(256) void scan_final(
    const float* __restrict__ delta, const float* __restrict__ x,
    const float* __restrict__ dbcBC, const float* __restrict__ A2T,
    const float* __restrict__ hin, const float* __restrict__ Dp,
    float* __restrict__ out)
{
    int tid = blockIdx.x * 256 + threadIdx.x;  // 131072
    int d = tid & (DINNER - 1);
    int c = (tid >> 11) & (NCHUNK - 1);
    int b = tid >> 16;
    float a2[DSTATE], h[DSTATE];
    size_t idx = (size_t)(b * NCHUNK + c) * DINNER + d;
    const floatx4* i4 = (const floatx4*)(hin + idx * DSTATE);
#pragma unroll
    for (int qq = 0; qq < 4; ++qq) {
        floatx4 v = i4[qq];
#pragma unroll
        for (int j = 0; j < 4; ++j) h[qq * 4 + j] = v[j];
    }
#pragma unroll
    for (int s = 0; s < DSTATE; ++s) a2[s] = A2T[s * DINNER + d];
    float Dd = Dp[d];
    int l0 = c * LCHUNK;
#pragma unroll 2
    for (int i = 0; i < LCHUNK; ++i) {
        int bl = b * LSEQ + l0 + i;
        float dl = delta[(size_t)bl * DINNER + d];
        float xv = x[(size_t)bl * DINNER + d];
        const floatx4* Bp = (const floatx4*)(dbcBC + (size_t)bl * 32);
        const floatx4* Cp = Bp + 4;
        float du = dl * xv;
        float y = 0.f;
#pragma unroll
        for (int qq = 0; qq < 4; ++qq) {
            floatx4 Bq = Bp[qq];
            floatx4 Cq = Cp[qq];
#pragma unroll
            for (int j = 0; j < 4; ++j) {
                int s = qq * 4 + j;
                float dA = EXP2F(dl * a2[s]);
                h[s] = fmaf(dA, h[s], du * Bq[j]);
                y = fmaf(h[s], Cq[j], y);
            }
        }
        out[(size_t)bl * DINNER + d] = fmaf(Dd, xv, y);
    }
}

extern "C" void kernel_launch(void* const* d_in, const int* in_sizes, int n_in,
                              void* d_out, int out_size, void* d_ws, size_t ws_size,
                              hipStream_t stream) {
    const float* x    = (const float*)d_in[0];
    const float* Wdbc = (const float*)d_in[1];
    const float* bdbc = (const float*)d_in[2];
    const float* Wdt  = (const float*)d_in[3];
    const float* bdt  = (const float*)d_in[4];
    const float* Alog = (const float*)d_in[5];
    const float* Dp   = (const float*)d_in[6];
    float* out = (float*)d_out;

    char* w = (char*)d_ws;
    __hip_bfloat16* wdbch = (__hip_bfloat16*)w;  w += (size_t)NDBC * FEAT * 2;
    __hip_bfloat16* wdbcl = (__hip_bfloat16*)w;  w += (size_t)NDBC * FEAT * 2;
    __hip_bfloat16* wdth = (__hip_bfloat16*)w;   w += (size_t)DINNER * DTRANK * 2;
    __hip_bfloat16* wdtl = (__hip_bfloat16*)w;   w += (size_t)DINNER * DTRANK * 2;
    float* partial = (float*)w;                  w += (size_t)KSPLIT * BL * NDBC * 4;   // 21 MB
    float* dbcBC = (float*)w;                    w += (size_t)BL * 32 * 4;              // 0.5 MB
    __hip_bfloat16* dhi = (__hip_bfloat16*)w;    w += (size_t)BL * DTRANK * 2;          // 1 MB
    __hip_bfloat16* dlo = (__hip_bfloat16*)w;    w += (size_t)BL * DTRANK * 2;          // 1 MB
    float* delta = (float*)w;                    w += (size_t)BL * DINNER * 4;          // 33.6 MB
    float* A2T = (float*)w;                      w += (size_t)DSTATE * DINNER * 4;      // 0.13 MB
    float* hA = (float*)w;                       w += (size_t)BATCH * NCHUNK * DINNER * DSTATE * 4; // 8.4 MB
    float* sumd = (float*)w;                     w += (size_t)BATCH * NCHUNK * DINNER * 4;          // 0.5 MB

    hipLaunchKernelGGL(split_bf16, dim3(NDBC * FEAT / 8 / 256), dim3(256), 0, stream,
                       Wdbc, wdbch, wdbcl, NDBC * FEAT / 8);
    hipLaunchKernelGGL(split_bf16, dim3(DINNER * DTRANK / 8 / 256), dim3(256), 0, stream,
                       Wdt, wdth, wdtl, DINNER * DTRANK / 8);
    hipLaunchKernelGGL(prep_a2, dim3((DSTATE * DINNER) / 256), dim3(256), 0, stream, Alog, A2T);
    hipLaunchKernelGGL(gemm_dbc, dim3(BL / 64, KSPLIT), dim3(256), 0, stream,
                       x, wdbch, wdbcl, partial);
    hipLaunchKernelGGL(finalize_dbc, dim3(BL * 40 / 256), dim3(256), 0, stream,
                       partial, bdbc, dbcBC, dhi, dlo);
    hipLaunchKernelGGL(gemm_dt, dim3(BL / 128, DINNER / 64), dim3(256), 0, stream,
                       dhi, dlo, wdth, wdtl, bdt, delta);
    hipLaunchKernelGGL(scan_partial, dim3((BATCH * NCHUNK * DINNER) / 256), dim3(256), 0, stream,
                       delta, x, dbcBC, A2T, hA, sumd);
    hipLaunchKernelGGL(scan_combine, dim3((BATCH * DINNER * DSTATE) / 256), dim3(256), 0, stream,
                       hA, sumd, A2T);
    hipLaunchKernelGGL(scan_final, dim3((BATCH * NCHUNK * DINNER) / 256), dim3(256), 0, stream,
                       delta, x, dbcBC, A2T, hA, Dp, out);
}

// Round 4
// 230.996 us; speedup vs baseline: 1.4148x; 1.3177x over previous
//
#include <hip/hip_runtime.h>
#include <hip/hip_bf16.h>
#include <math.h>

#define BATCH  2
#define LSEQ   2048
#define FEAT   2048
#define DINNER 2048
#define DSTATE 16
#define DTRANK 128
#define NDBC   160             // DT_RANK + 2*D_STATE
#define NCHUNK 64
#define LCHUNK (LSEQ / NCHUNK) // 32
#define BL     (BATCH * LSEQ)  // 4096
#define KSPLIT 8
#define KCH    (FEAT / KSPLIT) // 256
#define KSUB   64
#define BSTRIDE 72             // LDS row stride (bf16): 144 B = 9*16 B -> conflict-safe b128

typedef __attribute__((ext_vector_type(8))) short bf16x8;
typedef __attribute__((ext_vector_type(4))) short bf16x4;
typedef __attribute__((ext_vector_type(4))) float floatx4;

#if __has_builtin(__builtin_amdgcn_exp2f)
#define EXP2F(x) __builtin_amdgcn_exp2f(x)
#else
#define EXP2F(x) exp2f(x)
#endif

__device__ inline void split8(floatx4 a0, floatx4 a1, bf16x8* h, bf16x8* l) {
    union { bf16x8 v; __hip_bfloat16 e[8]; } H, L;
    float v[8] = {a0[0], a0[1], a0[2], a0[3], a1[0], a1[1], a1[2], a1[3]};
#pragma unroll
    for (int i = 0; i < 8; ++i) {
        H.e[i] = __float2bfloat16(v[i]);
        L.e[i] = __float2bfloat16(v[i] - __bfloat162float(H.e[i]));
    }
    *h = H.v; *l = L.v;
}

// ---------------- split fp32 -> bf16 hi + lo (weights only) ----------------
__global__ __launch_bounds__(256) void split_bf16(const float* __restrict__ src,
                                                  __hip_bfloat16* __restrict__ hi,
                                                  __hip_bfloat16* __restrict__ lo,
                                                  int n8) {
    int t = blockIdx.x * 256 + threadIdx.x;
    if (t >= n8) return;
    const floatx4* s4 = (const floatx4*)(src) + t * 2;
    bf16x8 h, l;
    split8(s4[0], s4[1], &h, &l);
    ((bf16x8*)hi)[t] = h;
    ((bf16x8*)lo)[t] = l;
}

// ---------------- A2T[s][d] = -exp(A_log[d][s]) * log2(e) ----------------
__global__ __launch_bounds__(256) void prep_a2(const float* __restrict__ Alog,
                                               float* __restrict__ A2T) {
    int tid = blockIdx.x * 256 + threadIdx.x;   // 32768
    int s = tid >> 11;
    int d = tid & (DINNER - 1);
    A2T[s * DINNER + d] = -__expf(Alog[d * DSTATE + s]) * 1.4426950408889634f;
}

// ---------------- GEMM1 split-K: partial[ks] = x(chunk) @ W_dbc(chunk)^T ----------------
__global__ __launch_bounds__(256) void gemm_dbc(
    const float* __restrict__ x,
    const __hip_bfloat16* __restrict__ wh, const __hip_bfloat16* __restrict__ wl,
    float* __restrict__ partial)
{
    __shared__ __hip_bfloat16 Bh[NDBC * BSTRIDE];
    __shared__ __hip_bfloat16 Bl[NDBC * BSTRIDE];
    int mt = blockIdx.x, ks = blockIdx.y;
    int t = threadIdx.x;
    int wave = t >> 6, lane = t & 63, lm = lane & 15, q = lane >> 4;
    int m0 = mt * 64;
    int k0 = ks * KCH;
    const float* xrow = x + (size_t)(m0 + wave * 16 + lm) * FEAT;
    floatx4 acc[10];
#pragma unroll
    for (int i = 0; i < 10; ++i) acc[i] = (floatx4){0.f, 0.f, 0.f, 0.f};
    int sr = t >> 3, scb = t & 7;
    for (int kc = 0; kc < KCH; kc += KSUB) {
#pragma unroll
        for (int r = sr; r < NDBC; r += 32) {
            size_t g = (size_t)r * FEAT + k0 + kc + scb * 8;
            *(bf16x8*)&Bh[r * BSTRIDE + scb * 8] = *(const bf16x8*)&wh[g];
            *(bf16x8*)&Bl[r * BSTRIDE + scb * 8] = *(const bf16x8*)&wl[g];
        }
        __syncthreads();
#pragma unroll
        for (int kk = 0; kk < KSUB; kk += 32) {
            int col = k0 + kc + kk + q * 8;
            floatx4 a0 = *(const floatx4*)(xrow + col);
            floatx4 a1 = *(const floatx4*)(xrow + col + 4);
            bf16x8 ah, al;
            split8(a0, a1, &ah, &al);
#pragma unroll
            for (int nt = 0; nt < 10; ++nt) {
                int boff = (nt * 16 + lm) * BSTRIDE + kk + q * 8;
                bf16x8 bh = *(const bf16x8*)&Bh[boff];
                bf16x8 bl = *(const bf16x8*)&Bl[boff];
                acc[nt] = __builtin_amdgcn_mfma_f32_16x16x32_bf16(ah, bh, acc[nt], 0, 0, 0);
                acc[nt] = __builtin_amdgcn_mfma_f32_16x16x32_bf16(ah, bl, acc[nt], 0, 0, 0);
                acc[nt] = __builtin_amdgcn_mfma_f32_16x16x32_bf16(al, bh, acc[nt], 0, 0, 0);
            }
        }
        __syncthreads();
    }
    float* pout = partial + ((size_t)ks * BL + m0 + wave * 16 + q * 4) * NDBC;
#pragma unroll
    for (int nt = 0; nt < 10; ++nt)
#pragma unroll
        for (int i = 0; i < 4; ++i)
            pout[(size_t)i * NDBC + nt * 16 + lm] = acc[nt][i];
}

// ---------------- finalize: sum K-partials + bias -> dbcBC fp32 + delta_lo hi/lo ----------------
__global__ __launch_bounds__(256) void finalize_dbc(
    const float* __restrict__ partial, const float* __restrict__ bias,
    float* __restrict__ dbcBC, __hip_bfloat16* __restrict__ dhi, __hip_bfloat16* __restrict__ dlo)
{
    int tid = blockIdx.x * 256 + threadIdx.x;  // 163840
    int m = tid / 40, c4 = tid - m * 40;
    int n = c4 * 4;
    floatx4 s = *(const floatx4*)(bias + n);
#pragma unroll
    for (int ks = 0; ks < KSPLIT; ++ks) {
        floatx4 p = *(const floatx4*)(partial + ((size_t)ks * BL + m) * NDBC + n);
        s = s + p;
    }
    if (c4 < 32) {
        union { bf16x4 v; __hip_bfloat16 e[4]; } H, L;
#pragma unroll
        for (int i = 0; i < 4; ++i) {
            H.e[i] = __float2bfloat16(s[i]);
            L.e[i] = __float2bfloat16(s[i] - __bfloat162float(H.e[i]));
        }
        *(bf16x4*)(dhi + (size_t)m * DTRANK + n) = H.v;
        *(bf16x4*)(dlo + (size_t)m * DTRANK + n) = L.v;
    } else {
        *(floatx4*)(dbcBC + (size_t)m * 32 + (n - 128)) = s;
    }
}

// ---------------- GEMM2: delta = softplus(delta_lo @ W_dt^T + b_dt) ----------------
__global__ __launch_bounds__(256) void gemm_dt(
    const __hip_bfloat16* __restrict__ dhi, const __hip_bfloat16* __restrict__ dlo,
    const __hip_bfloat16* __restrict__ wh, const __hip_bfloat16* __restrict__ wl,
    const float* __restrict__ bdt, float* __restrict__ delta)
{
    int mt = blockIdx.x, ntb = blockIdx.y;   // (32, 32)
    int t = threadIdx.x, wave = t >> 6, lane = t & 63, lm = lane & 15, q = lane >> 4;
    int m0 = mt * 128 + wave * 32;
    int n0 = ntb * 64;
    bf16x8 AH[2][4], AL[2][4];
#pragma unroll
    for (int sub = 0; sub < 2; ++sub) {
        const __hip_bfloat16* ah = dhi + (size_t)(m0 + sub * 16 + lm) * DTRANK + q * 8;
        const __hip_bfloat16* al = dlo + (size_t)(m0 + sub * 16 + lm) * DTRANK + q * 8;
#pragma unroll
        for (int kp = 0; kp < 4; ++kp) {
            AH[sub][kp] = *(const bf16x8*)(ah + kp * 32);
            AL[sub][kp] = *(const bf16x8*)(al + kp * 32);
        }
    }
    floatx4 acc[4][2];
#pragma unroll
    for (int i = 0; i < 4; ++i)
#pragma unroll
        for (int j = 0; j < 2; ++j) acc[i][j] = (floatx4){0.f, 0.f, 0.f, 0.f};
#pragma unroll
    for (int nt = 0; nt < 4; ++nt) {
        const __hip_bfloat16* bh = wh + (size_t)(n0 + nt * 16 + lm) * DTRANK + q * 8;
        const __hip_bfloat16* blp = wl + (size_t)(n0 + nt * 16 + lm) * DTRANK + q * 8;
#pragma unroll
        for (int kp = 0; kp < 4; ++kp) {
            bf16x8 bhv = *(const bf16x8*)(bh + kp * 32);
            bf16x8 blv = *(const bf16x8*)(blp + kp * 32);
#pragma unroll
            for (int sub = 0; sub < 2; ++sub) {
                acc[nt][sub] = __builtin_amdgcn_mfma_f32_16x16x32_bf16(AH[sub][kp], bhv, acc[nt][sub], 0, 0, 0);
                acc[nt][sub] = __builtin_amdgcn_mfma_f32_16x16x32_bf16(AH[sub][kp], blv, acc[nt][sub], 0, 0, 0);
                acc[nt][sub] = __builtin_amdgcn_mfma_f32_16x16x32_bf16(AL[sub][kp], bhv, acc[nt][sub], 0, 0, 0);
            }
        }
    }
#pragma unroll
    for (int nt = 0; nt < 4; ++nt) {
        int n = n0 + nt * 16 + lm;
        float bias = bdt[n];
#pragma unroll
        for (int sub = 0; sub < 2; ++sub)
#pragma unroll
            for (int i = 0; i < 4; ++i) {
                int m = m0 + sub * 16 + q * 4 + i;
                float v = acc[nt][sub][i] + bias;
                float sp = fmaxf(v, 0.f) + log1pf(__expf(-fabsf(v)));
                delta[(size_t)m * DINNER + n] = sp;
            }
    }
}

// ---------------- Pass A: chunk-local scan, software-pipelined ----------------
__global__ __launch_bounds__(256) void scan_partial(
    const float* __restrict__ delta, const float* __restrict__ x,
    const float* __restrict__ dbcBC, const float* __restrict__ A2T,
    float* __restrict__ hA, float* __restrict__ sumd)
{
    int tid = blockIdx.x * 256 + threadIdx.x;  // 262144
    int d = tid & (DINNER - 1);
    int c = (tid >> 11) & (NCHUNK - 1);
    int b = tid >> 17;
    float a2[DSTATE], h[DSTATE];
#pragma unroll
    for (int s = 0; s < DSTATE; ++s) { a2[s] = A2T[s * DINNER + d]; h[s] = 0.f; }
    int l0 = c * LCHUNK;
    size_t base = (size_t)(b * LSEQ + l0) * DINNER + d;
    size_t bbase = (size_t)(b * LSEQ + l0) * 32;
    // prologue: load iteration 0
    float dl = delta[base];
    float xv = x[base];
    floatx4 Bv0 = *(const floatx4*)(dbcBC + bbase);
    floatx4 Bv1 = *(const floatx4*)(dbcBC + bbase + 4);
    floatx4 Bv2 = *(const floatx4*)(dbcBC + bbase + 8);
    floatx4 Bv3 = *(const floatx4*)(dbcBC + bbase + 12);
    float sd = 0.f;
    for (int i = 0; i < LCHUNK - 1; ++i) {
        // prefetch i+1
        float dln = delta[base + (size_t)(i + 1) * DINNER];
        float xvn = x[base + (size_t)(i + 1) * DINNER];
        const floatx4* Bp = (const floatx4*)(dbcBC + bbase + (size_t)(i + 1) * 32);
        floatx4 Bn0 = Bp[0], Bn1 = Bp[1], Bn2 = Bp[2], Bn3 = Bp[3];
        // compute i
        float du = dl * xv;
        sd += dl;
        floatx4 Bq[4] = {Bv0, Bv1, Bv2, Bv3};
#pragma unroll
        for (int qq = 0; qq < 4; ++qq)
#pragma unroll
            for (int j = 0; j < 4; ++j) {
                int s = qq * 4 + j;
                float dA = EXP2F(dl * a2[s]);
                h[s] = fmaf(dA, h[s], du * Bq[qq][j]);
            }
        dl = dln; xv = xvn; Bv0 = Bn0; Bv1 = Bn1; Bv2 = Bn2; Bv3 = Bn3;
    }
    {   // epilogue: last iteration
        float du = dl * xv;
        sd += dl;
        floatx4 Bq[4] = {Bv0, Bv1, Bv2, Bv3};
#pragma unroll
        for (int qq = 0; qq < 4; ++qq)
#pragma unroll
            for (int j = 0; j < 4; ++j) {
                int s = qq * 4 + j;
                float dA = EXP2F(dl * a2[s]);
                h[s] = fmaf(dA, h[s], du * Bq[qq][j]);
            }
    }
    size_t idx = (size_t)(b * NCHUNK + c) * DINNER + d;
    floatx4* o4 = (floatx4*)(hA + idx * DSTATE);
#pragma unroll
    for (int qq = 0; qq < 4; ++qq) {
        floatx4 v = {h[qq * 4], h[qq * 4 + 1], h[qq * 4 + 2], h[qq * 4 + 3]};
        o4[qq] = v;
    }
    sumd[idx] = sd;
}

// ---------------- Pass B: exclusive combine across chunks (in-place hA -> h_in) ----
__global__ __launch_bounds__(256) void scan_combine(
    float* __restrict__ hA, const float* __restrict__ sumd, const float* __restrict__ A2T)
{
    int tid = blockIdx.x * 256 + threadIdx.x;  // 65536
    int s = tid & 15;
    int d = (tid >> 4) & (DINNER - 1);
    int b = tid >> 15;
    float a2s = A2T[s * DINNER + d];
    float hin = 0.f;
    size_t idx0 = (size_t)(b * NCHUNK) * DINNER + d;
    float sd_c = sumd[idx0];
    float hA_c = hA[idx0 * DSTATE + s];
    for (int c = 0; c < NCHUNK; ++c) {
        size_t idx = (size_t)(b * NCHUNK + c) * DINNER + d;
        float sd_n = 0.f, hA_n = 0.f;
        if (c + 1 < NCHUNK) {
            size_t idxn = idx + DINNER;
            sd_n = sumd[idxn];
            hA_n = hA[idxn * DSTATE + s];
        }
        hA[idx * DSTATE + s] = hin;
        hin = EXP2F(a2s * sd_c) * hin + hA_c;
        sd_c = sd_n; hA_c = hA_n;
    }
}

// ---------------- Pass C: re-scan chunks from h_in, emit y (pipelined) ----------------
__global__ __launch_bounds__(256) void scan_final(
    const float* __restrict__ delta, const float* __restrict__ x,
    const float* __restrict__ dbcBC, const float* __restrict__ A2T,
    const float* __restrict__ hin, const float* __restrict__ Dp,
    float* __restrict__ out)
{
    int tid = blockIdx.x * 256 + threadIdx.x;  // 262144
    int d = tid & (DINNER - 1);
    int c = (tid >> 11) & (NCHUNK - 1);
    int b = tid >> 17;
    float a2[DSTATE], h[DSTATE];
    size_t idx = (size_t)(b * NCHUNK + c) * DINNER + d;
    const floatx4* i4 = (const floatx4*)(hin + idx * DSTATE);
#pragma unroll
    for (int qq = 0; qq < 4; ++qq) {
        floatx4 v = i4[qq];
#pragma unroll
        for (int j = 0; j < 4; ++j) h[qq * 4 + j] = v[j];
    }
#pragma unroll
    for (int s = 0; s < DSTATE; ++s) a2[s] = A2T[s * DINNER + d];
    float Dd = Dp[d];
    int l0 = c * LCHUNK;
    size_t base = (size_t)(b * LSEQ + l0) * DINNER + d;
    size_t bbase = (size_t)(b * LSEQ + l0) * 32;
    float dl = delta[base];
    float xv = x[base];
    floatx4 Bv0 = *(const floatx4*)(dbcBC + bbase);
    floatx4 Bv1 = *(const floatx4*)(dbcBC + bbase + 4);
    floatx4 Bv2 = *(const floatx4*)(dbcBC + bbase + 8);
    floatx4 Bv3 = *(const floatx4*)(dbcBC + bbase + 12);
    floatx4 Cv0 = *(const floatx4*)(dbcBC + bbase + 16);
    floatx4 Cv1 = *(const floatx4*)(dbcBC + bbase + 20);
    floatx4 Cv2 = *(const floatx4*)(dbcBC + bbase + 24);
    floatx4 Cv3 = *(const floatx4*)(dbcBC + bbase + 28);
    for (int i = 0; i < LCHUNK - 1; ++i) {
        float dln = delta[base + (size_t)(i + 1) * DINNER];
        float xvn = x[base + (size_t)(i + 1) * DINNER];
        const floatx4* Pp = (const floatx4*)(dbcBC + bbase + (size_t)(i + 1) * 32);
        floatx4 Bn0 = Pp[0], Bn1 = Pp[1], Bn2 = Pp[2], Bn3 = Pp[3];
        floatx4 Cn0 = Pp[4], Cn1 = Pp[5], Cn2 = Pp[6], Cn3 = Pp[7];
        float du = dl * xv;
        float y = 0.f;
        floatx4 Bq[4] = {Bv0, Bv1, Bv2, Bv3};
        floatx4 Cq[4] = {Cv0, Cv1, Cv2, Cv3};
#pragma unroll
        for (int qq = 0; qq < 4; ++qq)
#pragma unroll
            for (int j = 0; j < 4; ++j) {
                int s = qq * 4 + j;
                float dA = EXP2F(dl * a2[s]);
                h[s] = fmaf(dA, h[s], du * Bq[qq][j]);
                y = fmaf(h[s], Cq[qq][j], y);
            }
        out[base + (size_t)i * DINNER] = fmaf(Dd, xv, y);
        dl = dln; xv = xvn;
        Bv0 = Bn0; Bv1 = Bn1; Bv2 = Bn2; Bv3 = Bn3;
        Cv0 = Cn0; Cv1 = Cn1; Cv2 = Cn2; Cv3 = Cn3;
    }
    {
        float du = dl * xv;
        float y = 0.f;
        floatx4 Bq[4] = {Bv0, Bv1, Bv2, Bv3};
        floatx4 Cq[4] = {Cv0, Cv1, Cv2, Cv3};
#pragma unroll
        for (int qq = 0; qq < 4; ++qq)
#pragma unroll
            for (int j = 0; j < 4; ++j) {
                int s = qq * 4 + j;
                float dA = EXP2F(dl * a2[s]);
                h[s] = fmaf(dA, h[s], du * Bq[qq][j]);
                y = fmaf(h[s], Cq[qq][j], y);
            }
        out[base + (size_t)(LCHUNK - 1) * DINNER] = fmaf(Dd, xv, y);
    }
}

extern "C" void kernel_launch(void* const* d_in, const int* in_sizes, int n_in,
                              void* d_out, int out_size, void* d_ws, size_t ws_size,
                              hipStream_t stream) {
    const float* x    = (const float*)d_in[0];
    const float* Wdbc = (const float*)d_in[1];
    const float* bdbc = (const float*)d_in[2];
    const float* Wdt  = (const float*)d_in[3];
    const float* bdt  = (const float*)d_in[4];
    const float* Alog = (const float*)d_in[5];
    const float* Dp   = (const float*)d_in[6];
    float* out = (float*)d_out;

    char* w = (char*)d_ws;
    __hip_bfloat16* wdbch = (__hip_bfloat16*)w;  w += (size_t)NDBC * FEAT * 2;
    __hip_bfloat16* wdbcl = (__hip_bfloat16*)w;  w += (size_t)NDBC * FEAT * 2;
    __hip_bfloat16* wdth = (__hip_bfloat16*)w;   w += (size_t)DINNER * DTRANK * 2;
    __hip_bfloat16* wdtl = (__hip_bfloat16*)w;   w += (size_t)DINNER * DTRANK * 2;
    float* partial = (float*)w;                  w += (size_t)KSPLIT * BL * NDBC * 4;   // 21 MB
    float* dbcBC = (float*)w;                    w += (size_t)BL * 32 * 4;              // 0.5 MB
    __hip_bfloat16* dhi = (__hip_bfloat16*)w;    w += (size_t)BL * DTRANK * 2;          // 1 MB
    __hip_bfloat16* dlo = (__hip_bfloat16*)w;    w += (size_t)BL * DTRANK * 2;          // 1 MB
    float* delta = (float*)w;                    w += (size_t)BL * DINNER * 4;          // 33.6 MB
    float* A2T = (float*)w;                      w += (size_t)DSTATE * DINNER * 4;      // 0.13 MB
    float* hA = (float*)w;                       w += (size_t)BATCH * NCHUNK * DINNER * DSTATE * 4; // 16.8 MB
    float* sumd = (float*)w;                     w += (size_t)BATCH * NCHUNK * DINNER * 4;          // 1 MB

    hipLaunchKernelGGL(split_bf16, dim3(NDBC * FEAT / 8 / 256), dim3(256), 0, stream,
                       Wdbc, wdbch, wdbcl, NDBC * FEAT / 8);
    hipLaunchKernelGGL(split_bf16, dim3(DINNER * DTRANK / 8 / 256), dim3(256), 0, stream,
                       Wdt, wdth, wdtl, DINNER * DTRANK / 8);
    hipLaunchKernelGGL(prep_a2, dim3((DSTATE * DINNER) / 256), dim3(256), 0, stream, Alog, A2T);
    hipLaunchKernelGGL(gemm_dbc, dim3(BL / 64, KSPLIT), dim3(256), 0, stream,
                       x, wdbch, wdbcl, partial);
    hipLaunchKernelGGL(finalize_dbc, dim3(BL * 40 / 256), dim3(256), 0, stream,
                       partial, bdbc, dbcBC, dhi, dlo);
    hipLaunchKernelGGL(gemm_dt, dim3(BL / 128, DINNER / 64), dim3(256), 0, stream,
                       dhi, dlo, wdth, wdtl, bdt, delta);
    hipLaunchKernelGGL(scan_partial, dim3((BATCH * NCHUNK * DINNER) / 256), dim3(256), 0, stream,
                       delta, x, dbcBC, A2T, hA, sumd);
    hipLaunchKernelGGL(scan_combine, dim3((BATCH * DINNER * DSTATE) / 256), dim3(256), 0, stream,
                       hA, sumd, A2T);
    hipLaunchKernelGGL(scan_final, dim3((BATCH * NCHUNK * DINNER) / 256), dim3(256), 0, stream,
                       delta, x, dbcBC, A2T, hA, Dp, out);
}

// Round 5
// 226.739 us; speedup vs baseline: 1.4413x; 1.0188x over previous
//
#include <hip/hip_runtime.h>
#include <hip/hip_bf16.h>
#include <math.h>

#define BATCH  2
#define LSEQ   2048
#define FEAT   2048
#define DINNER 2048
#define DSTATE 16
#define DTRANK 128
#define NDBC   160             // DT_RANK + 2*D_STATE
#define NCHUNK 64
#define LCHUNK (LSEQ / NCHUNK) // 32
#define BL     (BATCH * LSEQ)  // 4096
#define KSPLIT 8
#define KCH    (FEAT / KSPLIT) // 256
#define KSUB   64
#define BSTRIDE 72             // LDS row stride (bf16): conflict-safe b128

typedef __attribute__((ext_vector_type(8))) short bf16x8;
typedef __attribute__((ext_vector_type(4))) short bf16x4;
typedef __attribute__((ext_vector_type(4))) float floatx4;

#if __has_builtin(__builtin_amdgcn_exp2f)
#define EXP2F(x) __builtin_amdgcn_exp2f(x)
#else
#define EXP2F(x) exp2f(x)
#endif

__device__ inline void split8(floatx4 a0, floatx4 a1, bf16x8* h, bf16x8* l) {
    union { bf16x8 v; __hip_bfloat16 e[8]; } H, L;
    float v[8] = {a0[0], a0[1], a0[2], a0[3], a1[0], a1[1], a1[2], a1[3]};
#pragma unroll
    for (int i = 0; i < 8; ++i) {
        H.e[i] = __float2bfloat16(v[i]);
        L.e[i] = __float2bfloat16(v[i] - __bfloat162float(H.e[i]));
    }
    *h = H.v; *l = L.v;
}

// ---------------- split fp32 -> bf16 hi + lo (weights only) ----------------
__global__ __launch_bounds__(256) void split_bf16(const float* __restrict__ src,
                                                  __hip_bfloat16* __restrict__ hi,
                                                  __hip_bfloat16* __restrict__ lo,
                                                  int n8) {
    int t = blockIdx.x * 256 + threadIdx.x;
    if (t >= n8) return;
    const floatx4* s4 = (const floatx4*)(src) + t * 2;
    bf16x8 h, l;
    split8(s4[0], s4[1], &h, &l);
    ((bf16x8*)hi)[t] = h;
    ((bf16x8*)lo)[t] = l;
}

// ---------------- A2T[s][d] = -exp(A_log[d][s]) * log2(e) ----------------
__global__ __launch_bounds__(256) void prep_a2(const float* __restrict__ Alog,
                                               float* __restrict__ A2T) {
    int tid = blockIdx.x * 256 + threadIdx.x;   // 32768
    int s = tid >> 11;
    int d = tid & (DINNER - 1);
    A2T[s * DINNER + d] = -__expf(Alog[d * DSTATE + s]) * 1.4426950408889634f;
}

// ---------------- GEMM1 split-K: partial[ks] = x(chunk) @ W_dbc(chunk)^T ----------------
__global__ __launch_bounds__(256) void gemm_dbc(
    const float* __restrict__ x,
    const __hip_bfloat16* __restrict__ wh, const __hip_bfloat16* __restrict__ wl,
    float* __restrict__ partial)
{
    __shared__ union {
        struct { __hip_bfloat16 Bh[NDBC * BSTRIDE]; __hip_bfloat16 Bl[NDBC * BSTRIDE]; } s;
        float tile[64 * 164];   // 41984 B <= 46080 B
    } sm;
    int mt = blockIdx.x, ks = blockIdx.y;
    int t = threadIdx.x;
    int wave = t >> 6, lane = t & 63, lm = lane & 15, q = lane >> 4;
    int m0 = mt * 64;
    int k0 = ks * KCH;
    const float* xrow = x + (size_t)(m0 + wave * 16 + lm) * FEAT;
    floatx4 acc[10];
#pragma unroll
    for (int i = 0; i < 10; ++i) acc[i] = (floatx4){0.f, 0.f, 0.f, 0.f};
    int sr = t >> 3, scb = t & 7;
    for (int kc = 0; kc < KCH; kc += KSUB) {
#pragma unroll
        for (int r = sr; r < NDBC; r += 32) {
            size_t g = (size_t)r * FEAT + k0 + kc + scb * 8;
            *(bf16x8*)&sm.s.Bh[r * BSTRIDE + scb * 8] = *(const bf16x8*)&wh[g];
            *(bf16x8*)&sm.s.Bl[r * BSTRIDE + scb * 8] = *(const bf16x8*)&wl[g];
        }
        __syncthreads();
#pragma unroll
        for (int kk = 0; kk < KSUB; kk += 32) {
            int col = k0 + kc + kk + q * 8;
            floatx4 a0 = *(const floatx4*)(xrow + col);
            floatx4 a1 = *(const floatx4*)(xrow + col + 4);
            bf16x8 ah, al;
            split8(a0, a1, &ah, &al);
#pragma unroll
            for (int nt = 0; nt < 10; ++nt) {
                int boff = (nt * 16 + lm) * BSTRIDE + kk + q * 8;
                bf16x8 bh = *(const bf16x8*)&sm.s.Bh[boff];
                bf16x8 bl = *(const bf16x8*)&sm.s.Bl[boff];
                acc[nt] = __builtin_amdgcn_mfma_f32_16x16x32_bf16(ah, bh, acc[nt], 0, 0, 0);
                acc[nt] = __builtin_amdgcn_mfma_f32_16x16x32_bf16(ah, bl, acc[nt], 0, 0, 0);
                acc[nt] = __builtin_amdgcn_mfma_f32_16x16x32_bf16(al, bh, acc[nt], 0, 0, 0);
            }
        }
        __syncthreads();
    }
    // LDS epilogue -> coalesced float4 stores
#pragma unroll
    for (int nt = 0; nt < 10; ++nt)
#pragma unroll
        for (int i = 0; i < 4; ++i)
            sm.tile[(wave * 16 + q * 4 + i) * 164 + nt * 16 + lm] = acc[nt][i];
    __syncthreads();
#pragma unroll
    for (int it = 0; it < 10; ++it) {
        int idx = it * 256 + t;
        int row = idx / 40, cq = (idx - row * 40) * 4;
        floatx4 v = *(const floatx4*)&sm.tile[row * 164 + cq];
        *(floatx4*)&partial[((size_t)ks * BL + m0 + row) * NDBC + cq] = v;
    }
}

// ---------------- finalize: sum K-partials + bias -> dbcBC fp32 + delta_lo hi/lo ----------------
__global__ __launch_bounds__(256) void finalize_dbc(
    const float* __restrict__ partial, const float* __restrict__ bias,
    float* __restrict__ dbcBC, __hip_bfloat16* __restrict__ dhi, __hip_bfloat16* __restrict__ dlo)
{
    int tid = blockIdx.x * 256 + threadIdx.x;  // 163840
    int m = tid / 40, c4 = tid - m * 40;
    int n = c4 * 4;
    floatx4 s = *(const floatx4*)(bias + n);
#pragma unroll
    for (int ks = 0; ks < KSPLIT; ++ks) {
        floatx4 p = *(const floatx4*)(partial + ((size_t)ks * BL + m) * NDBC + n);
        s = s + p;
    }
    if (c4 < 32) {
        union { bf16x4 v; __hip_bfloat16 e[4]; } H, L;
#pragma unroll
        for (int i = 0; i < 4; ++i) {
            H.e[i] = __float2bfloat16(s[i]);
            L.e[i] = __float2bfloat16(s[i] - __bfloat162float(H.e[i]));
        }
        *(bf16x4*)(dhi + (size_t)m * DTRANK + n) = H.v;
        *(bf16x4*)(dlo + (size_t)m * DTRANK + n) = L.v;
    } else {
        *(floatx4*)(dbcBC + (size_t)m * 32 + (n - 128)) = s;
    }
}

// ---------------- GEMM2: delta = softplus(delta_lo @ W_dt^T + b_dt) ----------------
__global__ __launch_bounds__(256) void gemm_dt(
    const __hip_bfloat16* __restrict__ dhi, const __hip_bfloat16* __restrict__ dlo,
    const __hip_bfloat16* __restrict__ wh, const __hip_bfloat16* __restrict__ wl,
    const float* __restrict__ bdt, float* __restrict__ delta)
{
    __shared__ float tile[128 * 68];   // 34816 B
    int mt = blockIdx.x, ntb = blockIdx.y;   // (32, 32)
    int t = threadIdx.x, wave = t >> 6, lane = t & 63, lm = lane & 15, q = lane >> 4;
    int m0 = mt * 128 + wave * 32;
    int n0 = ntb * 64;
    bf16x8 AH[2][4], AL[2][4];
#pragma unroll
    for (int sub = 0; sub < 2; ++sub) {
        const __hip_bfloat16* ah = dhi + (size_t)(m0 + sub * 16 + lm) * DTRANK + q * 8;
        const __hip_bfloat16* al = dlo + (size_t)(m0 + sub * 16 + lm) * DTRANK + q * 8;
#pragma unroll
        for (int kp = 0; kp < 4; ++kp) {
            AH[sub][kp] = *(const bf16x8*)(ah + kp * 32);
            AL[sub][kp] = *(const bf16x8*)(al + kp * 32);
        }
    }
    floatx4 acc[4][2];
#pragma unroll
    for (int i = 0; i < 4; ++i)
#pragma unroll
        for (int j = 0; j < 2; ++j) acc[i][j] = (floatx4){0.f, 0.f, 0.f, 0.f};
#pragma unroll
    for (int nt = 0; nt < 4; ++nt) {
        const __hip_bfloat16* bh = wh + (size_t)(n0 + nt * 16 + lm) * DTRANK + q * 8;
        const __hip_bfloat16* blp = wl + (size_t)(n0 + nt * 16 + lm) * DTRANK + q * 8;
#pragma unroll
        for (int kp = 0; kp < 4; ++kp) {
            bf16x8 bhv = *(const bf16x8*)(bh + kp * 32);
            bf16x8 blv = *(const bf16x8*)(blp + kp * 32);
#pragma unroll
            for (int sub = 0; sub < 2; ++sub) {
                acc[nt][sub] = __builtin_amdgcn_mfma_f32_16x16x32_bf16(AH[sub][kp], bhv, acc[nt][sub], 0, 0, 0);
                acc[nt][sub] = __builtin_amdgcn_mfma_f32_16x16x32_bf16(AH[sub][kp], blv, acc[nt][sub], 0, 0, 0);
                acc[nt][sub] = __builtin_amdgcn_mfma_f32_16x16x32_bf16(AL[sub][kp], bhv, acc[nt][sub], 0, 0, 0);
            }
        }
    }
    // softplus + LDS epilogue -> coalesced stores
    int wrow = wave * 32;
#pragma unroll
    for (int nt = 0; nt < 4; ++nt) {
        float bias = bdt[n0 + nt * 16 + lm];
#pragma unroll
        for (int sub = 0; sub < 2; ++sub)
#pragma unroll
            for (int i = 0; i < 4; ++i) {
                float v = acc[nt][sub][i] + bias;
                float sp = fmaxf(v, 0.f) + log1pf(__expf(-fabsf(v)));
                tile[(wrow + sub * 16 + q * 4 + i) * 68 + nt * 16 + lm] = sp;
            }
    }
    __syncthreads();
#pragma unroll
    for (int it = 0; it < 8; ++it) {
        int idx = it * 256 + t;
        int row = idx >> 4, cq = (idx & 15) * 4;
        floatx4 v = *(const floatx4*)&tile[row * 68 + cq];
        *(floatx4*)&delta[(size_t)(mt * 128 + row) * DINNER + n0 + cq] = v;
    }
}

// ---------------- Pass A: chunk-local scan; B staged in LDS ----------------
__global__ __launch_bounds__(256) void scan_partial(
    const float* __restrict__ delta, const float* __restrict__ x,
    const float* __restrict__ dbcBC, const float* __restrict__ A2T,
    float* __restrict__ hA, float* __restrict__ sumd)
{
    __shared__ float BC[LCHUNK * 32];  // 4 KB
    int t = threadIdx.x;
    int gtid = blockIdx.x * 256 + t;
    int d = gtid & (DINNER - 1);
    int c = (gtid >> 11) & (NCHUNK - 1);
    int b = gtid >> 17;
    {
        int row = t >> 3, cq = (t & 7) * 4;
        *(floatx4*)&BC[row * 32 + cq] =
            *(const floatx4*)&dbcBC[(size_t)(b * LSEQ + c * LCHUNK + row) * 32 + cq];
    }
    float a2[DSTATE], h[DSTATE];
#pragma unroll
    for (int s = 0; s < DSTATE; ++s) { a2[s] = A2T[s * DINNER + d]; h[s] = 0.f; }
    __syncthreads();
    const float* dp = delta + (size_t)(b * LSEQ + c * LCHUNK) * DINNER + d;
    const float* xp = x + (size_t)(b * LSEQ + c * LCHUNK) * DINNER + d;
    float dl = *dp, xv = *xp, sd = 0.f;
    for (int i = 0; i < LCHUNK - 1; ++i) {
        dp += DINNER; xp += DINNER;
        float dln = *dp, xvn = *xp;
        float du = dl * xv;
        sd += dl;
        const floatx4* Bq = (const floatx4*)&BC[i * 32];
#pragma unroll
        for (int qq = 0; qq < 4; ++qq) {
            floatx4 Bv = Bq[qq];
#pragma unroll
            for (int j = 0; j < 4; ++j) {
                int s = qq * 4 + j;
                h[s] = fmaf(EXP2F(dl * a2[s]), h[s], du * Bv[j]);
            }
        }
        dl = dln; xv = xvn;
    }
    {
        float du = dl * xv;
        sd += dl;
        const floatx4* Bq = (const floatx4*)&BC[(LCHUNK - 1) * 32];
#pragma unroll
        for (int qq = 0; qq < 4; ++qq) {
            floatx4 Bv = Bq[qq];
#pragma unroll
            for (int j = 0; j < 4; ++j) {
                int s = qq * 4 + j;
                h[s] = fmaf(EXP2F(dl * a2[s]), h[s], du * Bv[j]);
            }
        }
    }
    // hA layout [b][c][q][d][4] -> coalesced float4
    size_t hbase = ((size_t)((b * NCHUNK + c) * 4) * DINNER + d) * 4;
#pragma unroll
    for (int qq = 0; qq < 4; ++qq) {
        floatx4 v = {h[qq * 4], h[qq * 4 + 1], h[qq * 4 + 2], h[qq * 4 + 3]};
        *(floatx4*)&hA[hbase + (size_t)qq * DINNER * 4] = v;
    }
    sumd[(size_t)(b * NCHUNK + c) * DINNER + d] = sd;
}

// ---------------- Pass B: exclusive combine, 16-wide batched loads ----------------
__global__ __launch_bounds__(256) void scan_combine(
    float* __restrict__ hA, const float* __restrict__ sumd, const float* __restrict__ A2T)
{
    int tid = blockIdx.x * 256 + threadIdx.x;  // 65536
    int s = tid & 15;
    int d = (tid >> 4) & (DINNER - 1);
    int b = tid >> 15;
    float a2s = A2T[s * DINNER + d];
    int q = s >> 2, e = s & 3;
    size_t hoff = ((size_t)(b * NCHUNK * 4 + q) * DINNER + d) * 4 + e;  // c=0
    size_t soff = (size_t)(b * NCHUNK) * DINNER + d;
    const size_t hstep = (size_t)16 * DINNER;  // per-c stride in floats
    float hin = 0.f;
#pragma unroll
    for (int g = 0; g < NCHUNK / 16; ++g) {
        float sdv[16], hv[16];
#pragma unroll
        for (int k = 0; k < 16; ++k) {
            int cc = g * 16 + k;
            sdv[k] = sumd[soff + (size_t)cc * DINNER];
            hv[k] = hA[hoff + (size_t)cc * hstep];
        }
#pragma unroll
        for (int k = 0; k < 16; ++k) {
            int cc = g * 16 + k;
            hA[hoff + (size_t)cc * hstep] = hin;
            hin = EXP2F(a2s * sdv[k]) * hin + hv[k];
        }
    }
}

// ---------------- Pass C: re-scan chunks from h_in, emit y; B/C staged in LDS ----------------
__global__ __launch_bounds__(256) void scan_final(
    const float* __restrict__ delta, const float* __restrict__ x,
    const float* __restrict__ dbcBC, const float* __restrict__ A2T,
    const float* __restrict__ hin, const float* __restrict__ Dp,
    float* __restrict__ out)
{
    __shared__ float BC[LCHUNK * 32];  // 4 KB
    int t = threadIdx.x;
    int gtid = blockIdx.x * 256 + t;
    int d = gtid & (DINNER - 1);
    int c = (gtid >> 11) & (NCHUNK - 1);
    int b = gtid >> 17;
    {
        int row = t >> 3, cq = (t & 7) * 4;
        *(floatx4*)&BC[row * 32 + cq] =
            *(const floatx4*)&dbcBC[(size_t)(b * LSEQ + c * LCHUNK + row) * 32 + cq];
    }
    float a2[DSTATE], h[DSTATE];
    size_t hbase = ((size_t)((b * NCHUNK + c) * 4) * DINNER + d) * 4;
#pragma unroll
    for (int qq = 0; qq < 4; ++qq) {
        floatx4 v = *(const floatx4*)&hin[hbase + (size_t)qq * DINNER * 4];
#pragma unroll
        for (int j = 0; j < 4; ++j) h[qq * 4 + j] = v[j];
    }
#pragma unroll
    for (int s = 0; s < DSTATE; ++s) a2[s] = A2T[s * DINNER + d];
    float Dd = Dp[d];
    __syncthreads();
    size_t base = (size_t)(b * LSEQ + c * LCHUNK) * DINNER + d;
    const float* dp = delta + base;
    const float* xp = x + base;
    float* op = out + base;
    float dl = *dp, xv = *xp;
    for (int i = 0; i < LCHUNK - 1; ++i) {
        dp += DINNER; xp += DINNER;
        float dln = *dp, xvn = *xp;
        float du = dl * xv;
        float y = 0.f;
        const floatx4* Pq = (const floatx4*)&BC[i * 32];
#pragma unroll
        for (int qq = 0; qq < 4; ++qq) {
            floatx4 Bv = Pq[qq];
            floatx4 Cv = Pq[qq + 4];
#pragma unroll
            for (int j = 0; j < 4; ++j) {
                int s = qq * 4 + j;
                h[s] = fmaf(EXP2F(dl * a2[s]), h[s], du * Bv[j]);
                y = fmaf(h[s], Cv[j], y);
            }
        }
        *op = fmaf(Dd, xv, y);
        op += DINNER;
        dl = dln; xv = xvn;
    }
    {
        float du = dl * xv;
        float y = 0.f;
        const floatx4* Pq = (const floatx4*)&BC[(LCHUNK - 1) * 32];
#pragma unroll
        for (int qq = 0; qq < 4; ++qq) {
            floatx4 Bv = Pq[qq];
            floatx4 Cv = Pq[qq + 4];
#pragma unroll
            for (int j = 0; j < 4; ++j) {
                int s = qq * 4 + j;
                h[s] = fmaf(EXP2F(dl * a2[s]), h[s], du * Bv[j]);
                y = fmaf(h[s], Cv[j], y);
            }
        }
        *op = fmaf(Dd, xv, y);
    }
}

extern "C" void kernel_launch(void* const* d_in, const int* in_sizes, int n_in,
                              void* d_out, int out_size, void* d_ws, size_t ws_size,
                              hipStream_t stream) {
    const float* x    = (const float*)d_in[0];
    const float* Wdbc = (const float*)d_in[1];
    const float* bdbc = (const float*)d_in[2];
    const float* Wdt  = (const float*)d_in[3];
    const float* bdt  = (const float*)d_in[4];
    const float* Alog = (const float*)d_in[5];
    const float* Dp   = (const float*)d_in[6];
    float* out = (float*)d_out;

    char* w = (char*)d_ws;
    __hip_bfloat16* wdbch = (__hip_bfloat16*)w;  w += (size_t)NDBC * FEAT * 2;
    __hip_bfloat16* wdbcl = (__hip_bfloat16*)w;  w += (size_t)NDBC * FEAT * 2;
    __hip_bfloat16* wdth = (__hip_bfloat16*)w;   w += (size_t)DINNER * DTRANK * 2;
    __hip_bfloat16* wdtl = (__hip_bfloat16*)w;   w += (size_t)DINNER * DTRANK * 2;
    float* partial = (float*)w;                  w += (size_t)KSPLIT * BL * NDBC * 4;   // 21 MB
    float* dbcBC = (float*)w;                    w += (size_t)BL * 32 * 4;              // 0.5 MB
    __hip_bfloat16* dhi = (__hip_bfloat16*)w;    w += (size_t)BL * DTRANK * 2;          // 1 MB
    __hip_bfloat16* dlo = (__hip_bfloat16*)w;    w += (size_t)BL * DTRANK * 2;          // 1 MB
    float* delta = (float*)w;                    w += (size_t)BL * DINNER * 4;          // 33.6 MB
    float* A2T = (float*)w;                      w += (size_t)DSTATE * DINNER * 4;      // 0.13 MB
    float* hA = (float*)w;                       w += (size_t)BATCH * NCHUNK * DINNER * DSTATE * 4; // 16.8 MB
    float* sumd = (float*)w;                     w += (size_t)BATCH * NCHUNK * DINNER * 4;          // 1 MB

    hipLaunchKernelGGL(split_bf16, dim3(NDBC * FEAT / 8 / 256), dim3(256), 0, stream,
                       Wdbc, wdbch, wdbcl, NDBC * FEAT / 8);
    hipLaunchKernelGGL(split_bf16, dim3(DINNER * DTRANK / 8 / 256), dim3(256), 0, stream,
                       Wdt, wdth, wdtl, DINNER * DTRANK / 8);
    hipLaunchKernelGGL(prep_a2, dim3((DSTATE * DINNER) / 256), dim3(256), 0, stream, Alog, A2T);
    hipLaunchKernelGGL(gemm_dbc, dim3(BL / 64, KSPLIT), dim3(256), 0, stream,
                       x, wdbch, wdbcl, partial);
    hipLaunchKernelGGL(finalize_dbc, dim3(BL * 40 / 256), dim3(256), 0, stream,
                       partial, bdbc, dbcBC, dhi, dlo);
    hipLaunchKernelGGL(gemm_dt, dim3(BL / 128, DINNER / 64), dim3(256), 0, stream,
                       dhi, dlo, wdth, wdtl, bdt, delta);
    hipLaunchKernelGGL(scan_partial, dim3((BATCH * NCHUNK * DINNER) / 256), dim3(256), 0, stream,
                       delta, x, dbcBC, A2T, hA, sumd);
    hipLaunchKernelGGL(scan_combine, dim3((BATCH * DINNER * DSTATE) / 256), dim3(256), 0, stream,
                       hA, sumd, A2T);
    hipLaunchKernelGGL(scan_final, dim3((BATCH * NCHUNK * DINNER) / 256), dim3(256), 0, stream,
                       delta, x, dbcBC, A2T, hA, Dp, out);
}

// Round 6
// 211.657 us; speedup vs baseline: 1.5440x; 1.0713x over previous
//
#include <hip/hip_runtime.h>
#include <hip/hip_bf16.h>
#include <math.h>

#define BATCH  2
#define LSEQ   2048
#define FEAT   2048
#define DINNER 2048
#define DSTATE 16
#define DTRANK 128
#define NDBC   160             // DT_RANK + 2*D_STATE
#define NCHUNK 64
#define LCHUNK (LSEQ / NCHUNK) // 32
#define BL     (BATCH * LSEQ)  // 4096
#define KSPLIT 8
#define KCH    (FEAT / KSPLIT) // 256
#define KSUB   64
#define BSTRIDE 72             // LDS row stride (bf16): conflict-safe b128

typedef __attribute__((ext_vector_type(8))) short bf16x8;
typedef __attribute__((ext_vector_type(4))) short bf16x4;
typedef __attribute__((ext_vector_type(4))) float floatx4;

#if __has_builtin(__builtin_amdgcn_exp2f)
#define EXP2F(x) __builtin_amdgcn_exp2f(x)
#else
#define EXP2F(x) exp2f(x)
#endif
#if __has_builtin(__builtin_amdgcn_logf)
#define LOG2F(x) __builtin_amdgcn_logf(x)
#else
#define LOG2F(x) __log2f(x)
#endif

// softplus via HW transcendentals: max(v,0) + ln2*log2(1+2^(-|v|*log2e))
__device__ inline float softplus_fast(float v) {
    float e = EXP2F(-fabsf(v) * 1.4426950408889634f);
    return fmaxf(v, 0.f) + 0.6931471805599453f * LOG2F(1.f + e);
}

__device__ inline void split8(floatx4 a0, floatx4 a1, bf16x8* h, bf16x8* l) {
    union { bf16x8 v; __hip_bfloat16 e[8]; } H, L;
    float v[8] = {a0[0], a0[1], a0[2], a0[3], a1[0], a1[1], a1[2], a1[3]};
#pragma unroll
    for (int i = 0; i < 8; ++i) {
        H.e[i] = __float2bfloat16(v[i]);
        L.e[i] = __float2bfloat16(v[i] - __bfloat162float(H.e[i]));
    }
    *h = H.v; *l = L.v;
}

// ---------------- split fp32 -> bf16 hi + lo (weights only) ----------------
__global__ __launch_bounds__(256) void split_bf16(const float* __restrict__ src,
                                                  __hip_bfloat16* __restrict__ hi,
                                                  __hip_bfloat16* __restrict__ lo,
                                                  int n8) {
    int t = blockIdx.x * 256 + threadIdx.x;
    if (t >= n8) return;
    const floatx4* s4 = (const floatx4*)(src) + t * 2;
    bf16x8 h, l;
    split8(s4[0], s4[1], &h, &l);
    ((bf16x8*)hi)[t] = h;
    ((bf16x8*)lo)[t] = l;
}

// ---------------- A2T[s][d] = -exp(A_log[d][s]) * log2(e) ----------------
__global__ __launch_bounds__(256) void prep_a2(const float* __restrict__ Alog,
                                               float* __restrict__ A2T) {
    int tid = blockIdx.x * 256 + threadIdx.x;   // 32768
    int s = tid >> 11;
    int d = tid & (DINNER - 1);
    A2T[s * DINNER + d] = -__expf(Alog[d * DSTATE + s]) * 1.4426950408889634f;
}

// ---------------- GEMM1 split-K: partial[ks] = x(chunk) @ W_dbc(chunk)^T ----------------
__global__ __launch_bounds__(256) void gemm_dbc(
    const float* __restrict__ x,
    const __hip_bfloat16* __restrict__ wh, const __hip_bfloat16* __restrict__ wl,
    float* __restrict__ partial)
{
    __shared__ union {
        struct { __hip_bfloat16 Bh[NDBC * BSTRIDE]; __hip_bfloat16 Bl[NDBC * BSTRIDE]; } s;
        float tile[64 * 164];   // 41984 B <= 46080 B
    } sm;
    int mt = blockIdx.x, ks = blockIdx.y;
    int t = threadIdx.x;
    int wave = t >> 6, lane = t & 63, lm = lane & 15, q = lane >> 4;
    int m0 = mt * 64;
    int k0 = ks * KCH;
    const float* xrow = x + (size_t)(m0 + wave * 16 + lm) * FEAT;
    floatx4 acc[10];
#pragma unroll
    for (int i = 0; i < 10; ++i) acc[i] = (floatx4){0.f, 0.f, 0.f, 0.f};
    int sr = t >> 3, scb = t & 7;
    for (int kc = 0; kc < KCH; kc += KSUB) {
#pragma unroll
        for (int r = sr; r < NDBC; r += 32) {
            size_t g = (size_t)r * FEAT + k0 + kc + scb * 8;
            *(bf16x8*)&sm.s.Bh[r * BSTRIDE + scb * 8] = *(const bf16x8*)&wh[g];
            *(bf16x8*)&sm.s.Bl[r * BSTRIDE + scb * 8] = *(const bf16x8*)&wl[g];
        }
        __syncthreads();
#pragma unroll
        for (int kk = 0; kk < KSUB; kk += 32) {
            int col = k0 + kc + kk + q * 8;
            floatx4 a0 = *(const floatx4*)(xrow + col);
            floatx4 a1 = *(const floatx4*)(xrow + col + 4);
            bf16x8 ah, al;
            split8(a0, a1, &ah, &al);
#pragma unroll
            for (int nt = 0; nt < 10; ++nt) {
                int boff = (nt * 16 + lm) * BSTRIDE + kk + q * 8;
                bf16x8 bh = *(const bf16x8*)&sm.s.Bh[boff];
                bf16x8 bl = *(const bf16x8*)&sm.s.Bl[boff];
                acc[nt] = __builtin_amdgcn_mfma_f32_16x16x32_bf16(ah, bh, acc[nt], 0, 0, 0);
                acc[nt] = __builtin_amdgcn_mfma_f32_16x16x32_bf16(ah, bl, acc[nt], 0, 0, 0);
                acc[nt] = __builtin_amdgcn_mfma_f32_16x16x32_bf16(al, bh, acc[nt], 0, 0, 0);
            }
        }
        __syncthreads();
    }
    // LDS epilogue -> coalesced float4 stores
#pragma unroll
    for (int nt = 0; nt < 10; ++nt)
#pragma unroll
        for (int i = 0; i < 4; ++i)
            sm.tile[(wave * 16 + q * 4 + i) * 164 + nt * 16 + lm] = acc[nt][i];
    __syncthreads();
#pragma unroll
    for (int it = 0; it < 10; ++it) {
        int idx = it * 256 + t;
        int row = idx / 40, cq = (idx - row * 40) * 4;
        floatx4 v = *(const floatx4*)&sm.tile[row * 164 + cq];
        *(floatx4*)&partial[((size_t)ks * BL + m0 + row) * NDBC + cq] = v;
    }
}

// ---------------- finalize: sum K-partials + bias -> dbcBC fp32 + delta_lo hi/lo ----------------
__global__ __launch_bounds__(256) void finalize_dbc(
    const float* __restrict__ partial, const float* __restrict__ bias,
    float* __restrict__ dbcBC, __hip_bfloat16* __restrict__ dhi, __hip_bfloat16* __restrict__ dlo)
{
    int tid = blockIdx.x * 256 + threadIdx.x;  // 163840
    int m = tid / 40, c4 = tid - m * 40;
    int n = c4 * 4;
    floatx4 s = *(const floatx4*)(bias + n);
#pragma unroll
    for (int ks = 0; ks < KSPLIT; ++ks) {
        floatx4 p = *(const floatx4*)(partial + ((size_t)ks * BL + m) * NDBC + n);
        s = s + p;
    }
    if (c4 < 32) {
        union { bf16x4 v; __hip_bfloat16 e[4]; } H, L;
#pragma unroll
        for (int i = 0; i < 4; ++i) {
            H.e[i] = __float2bfloat16(s[i]);
            L.e[i] = __float2bfloat16(s[i] - __bfloat162float(H.e[i]));
        }
        *(bf16x4*)(dhi + (size_t)m * DTRANK + n) = H.v;
        *(bf16x4*)(dlo + (size_t)m * DTRANK + n) = L.v;
    } else {
        *(floatx4*)(dbcBC + (size_t)m * 32 + (n - 128)) = s;
    }
}

// ---------------- GEMM2: delta = softplus(delta_lo @ W_dt^T + b_dt) ----------------
__global__ __launch_bounds__(256) void gemm_dt(
    const __hip_bfloat16* __restrict__ dhi, const __hip_bfloat16* __restrict__ dlo,
    const __hip_bfloat16* __restrict__ wh, const __hip_bfloat16* __restrict__ wl,
    const float* __restrict__ bdt, float* __restrict__ delta)
{
    __shared__ float tile[128 * 68];   // 34816 B
    int mt = blockIdx.x, ntb = blockIdx.y;   // (32, 32)
    int t = threadIdx.x, wave = t >> 6, lane = t & 63, lm = lane & 15, q = lane >> 4;
    int m0 = mt * 128 + wave * 32;
    int n0 = ntb * 64;
    bf16x8 AH[2][4], AL[2][4];
#pragma unroll
    for (int sub = 0; sub < 2; ++sub) {
        const __hip_bfloat16* ah = dhi + (size_t)(m0 + sub * 16 + lm) * DTRANK + q * 8;
        const __hip_bfloat16* al = dlo + (size_t)(m0 + sub * 16 + lm) * DTRANK + q * 8;
#pragma unroll
        for (int kp = 0; kp < 4; ++kp) {
            AH[sub][kp] = *(const bf16x8*)(ah + kp * 32);
            AL[sub][kp] = *(const bf16x8*)(al + kp * 32);
        }
    }
    floatx4 acc[4][2];
#pragma unroll
    for (int i = 0; i < 4; ++i)
#pragma unroll
        for (int j = 0; j < 2; ++j) acc[i][j] = (floatx4){0.f, 0.f, 0.f, 0.f};
#pragma unroll
    for (int nt = 0; nt < 4; ++nt) {
        const __hip_bfloat16* bh = wh + (size_t)(n0 + nt * 16 + lm) * DTRANK + q * 8;
        const __hip_bfloat16* blp = wl + (size_t)(n0 + nt * 16 + lm) * DTRANK + q * 8;
#pragma unroll
        for (int kp = 0; kp < 4; ++kp) {
            bf16x8 bhv = *(const bf16x8*)(bh + kp * 32);
            bf16x8 blv = *(const bf16x8*)(blp + kp * 32);
#pragma unroll
            for (int sub = 0; sub < 2; ++sub) {
                acc[nt][sub] = __builtin_amdgcn_mfma_f32_16x16x32_bf16(AH[sub][kp], bhv, acc[nt][sub], 0, 0, 0);
                acc[nt][sub] = __builtin_amdgcn_mfma_f32_16x16x32_bf16(AH[sub][kp], blv, acc[nt][sub], 0, 0, 0);
                acc[nt][sub] = __builtin_amdgcn_mfma_f32_16x16x32_bf16(AL[sub][kp], bhv, acc[nt][sub], 0, 0, 0);
            }
        }
    }
    // fast softplus + LDS epilogue -> coalesced stores
    int wrow = wave * 32;
#pragma unroll
    for (int nt = 0; nt < 4; ++nt) {
        float bias = bdt[n0 + nt * 16 + lm];
#pragma unroll
        for (int sub = 0; sub < 2; ++sub)
#pragma unroll
            for (int i = 0; i < 4; ++i) {
                float v = acc[nt][sub][i] + bias;
                tile[(wrow + sub * 16 + q * 4 + i) * 68 + nt * 16 + lm] = softplus_fast(v);
            }
    }
    __syncthreads();
#pragma unroll
    for (int it = 0; it < 8; ++it) {
        int idx = it * 256 + t;
        int row = idx >> 4, cq = (idx & 15) * 4;
        floatx4 v = *(const floatx4*)&tile[row * 68 + cq];
        *(floatx4*)&delta[(size_t)(mt * 128 + row) * DINNER + n0 + cq] = v;
    }
}

// ---------------- Pass A: chunk-local scan; B staged in LDS ----------------
__global__ __launch_bounds__(256) void scan_partial(
    const float* __restrict__ delta, const float* __restrict__ x,
    const float* __restrict__ dbcBC, const float* __restrict__ A2T,
    float* __restrict__ hA, float* __restrict__ sumd)
{
    __shared__ float BC[LCHUNK * 32];  // 4 KB
    int t = threadIdx.x;
    int gtid = blockIdx.x * 256 + t;
    int d = gtid & (DINNER - 1);
    int c = (gtid >> 11) & (NCHUNK - 1);
    int b = gtid >> 17;
    {
        int row = t >> 3, cq = (t & 7) * 4;
        *(floatx4*)&BC[row * 32 + cq] =
            *(const floatx4*)&dbcBC[(size_t)(b * LSEQ + c * LCHUNK + row) * 32 + cq];
    }
    float a2[DSTATE], h[DSTATE];
#pragma unroll
    for (int s = 0; s < DSTATE; ++s) { a2[s] = A2T[s * DINNER + d]; h[s] = 0.f; }
    __syncthreads();
    const float* dp = delta + (size_t)(b * LSEQ + c * LCHUNK) * DINNER + d;
    const float* xp = x + (size_t)(b * LSEQ + c * LCHUNK) * DINNER + d;
    float dl = *dp, xv = *xp, sd = 0.f;
    for (int i = 0; i < LCHUNK - 1; ++i) {
        dp += DINNER; xp += DINNER;
        float dln = *dp, xvn = *xp;
        float du = dl * xv;
        sd += dl;
        const floatx4* Bq = (const floatx4*)&BC[i * 32];
#pragma unroll
        for (int qq = 0; qq < 4; ++qq) {
            floatx4 Bv = Bq[qq];
#pragma unroll
            for (int j = 0; j < 4; ++j) {
                int s = qq * 4 + j;
                h[s] = fmaf(EXP2F(dl * a2[s]), h[s], du * Bv[j]);
            }
        }
        dl = dln; xv = xvn;
    }
    {
        float du = dl * xv;
        sd += dl;
        const floatx4* Bq = (const floatx4*)&BC[(LCHUNK - 1) * 32];
#pragma unroll
        for (int qq = 0; qq < 4; ++qq) {
            floatx4 Bv = Bq[qq];
#pragma unroll
            for (int j = 0; j < 4; ++j) {
                int s = qq * 4 + j;
                h[s] = fmaf(EXP2F(dl * a2[s]), h[s], du * Bv[j]);
            }
        }
    }
    // hA layout [b][c][q][d][4] -> coalesced float4
    size_t hbase = ((size_t)((b * NCHUNK + c) * 4) * DINNER + d) * 4;
#pragma unroll
    for (int qq = 0; qq < 4; ++qq) {
        floatx4 v = {h[qq * 4], h[qq * 4 + 1], h[qq * 4 + 2], h[qq * 4 + 3]};
        *(floatx4*)&hA[hbase + (size_t)qq * DINNER * 4] = v;
    }
    sumd[(size_t)(b * NCHUNK + c) * DINNER + d] = sd;
}

// ---------------- Pass B: exclusive combine, 16-wide batched loads ----------------
__global__ __launch_bounds__(256) void scan_combine(
    float* __restrict__ hA, const float* __restrict__ sumd, const float* __restrict__ A2T)
{
    int tid = blockIdx.x * 256 + threadIdx.x;  // 65536
    int s = tid & 15;
    int d = (tid >> 4) & (DINNER - 1);
    int b = tid >> 15;
    float a2s = A2T[s * DINNER + d];
    int q = s >> 2, e = s & 3;
    size_t hoff = ((size_t)(b * NCHUNK * 4 + q) * DINNER + d) * 4 + e;  // c=0
    size_t soff = (size_t)(b * NCHUNK) * DINNER + d;
    const size_t hstep = (size_t)16 * DINNER;  // per-c stride in floats
    float hin = 0.f;
#pragma unroll
    for (int g = 0; g < NCHUNK / 16; ++g) {
        float sdv[16], hv[16];
#pragma unroll
        for (int k = 0; k < 16; ++k) {
            int cc = g * 16 + k;
            sdv[k] = sumd[soff + (size_t)cc * DINNER];
            hv[k] = hA[hoff + (size_t)cc * hstep];
        }
#pragma unroll
        for (int k = 0; k < 16; ++k) {
            int cc = g * 16 + k;
            hA[hoff + (size_t)cc * hstep] = hin;
            hin = EXP2F(a2s * sdv[k]) * hin + hv[k];
        }
    }
}

// ---------------- Pass C: re-scan chunks from h_in, emit y; B/C staged in LDS ----------------
__global__ __launch_bounds__(256) void scan_final(
    const float* __restrict__ delta, const float* __restrict__ x,
    const float* __restrict__ dbcBC, const float* __restrict__ A2T,
    const float* __restrict__ hin, const float* __restrict__ Dp,
    float* __restrict__ out)
{
    __shared__ float BC[LCHUNK * 32];  // 4 KB
    int t = threadIdx.x;
    int gtid = blockIdx.x * 256 + t;
    int d = gtid & (DINNER - 1);
    int c = (gtid >> 11) & (NCHUNK - 1);
    int b = gtid >> 17;
    {
        int row = t >> 3, cq = (t & 7) * 4;
        *(floatx4*)&BC[row * 32 + cq] =
            *(const floatx4*)&dbcBC[(size_t)(b * LSEQ + c * LCHUNK + row) * 32 + cq];
    }
    float a2[DSTATE], h[DSTATE];
    size_t hbase = ((size_t)((b * NCHUNK + c) * 4) * DINNER + d) * 4;
#pragma unroll
    for (int qq = 0; qq < 4; ++qq) {
        floatx4 v = *(const floatx4*)&hin[hbase + (size_t)qq * DINNER * 4];
#pragma unroll
        for (int j = 0; j < 4; ++j) h[qq * 4 + j] = v[j];
    }
#pragma unroll
    for (int s = 0; s < DSTATE; ++s) a2[s] = A2T[s * DINNER + d];
    float Dd = Dp[d];
    __syncthreads();
    size_t base = (size_t)(b * LSEQ + c * LCHUNK) * DINNER + d;
    const float* dp = delta + base;
    const float* xp = x + base;
    float* op = out + base;
    float dl = *dp, xv = *xp;
    for (int i = 0; i < LCHUNK - 1; ++i) {
        dp += DINNER; xp += DINNER;
        float dln = *dp, xvn = *xp;
        float du = dl * xv;
        float y = 0.f;
        const floatx4* Pq = (const floatx4*)&BC[i * 32];
#pragma unroll
        for (int qq = 0; qq < 4; ++qq) {
            floatx4 Bv = Pq[qq];
            floatx4 Cv = Pq[qq + 4];
#pragma unroll
            for (int j = 0; j < 4; ++j) {
                int s = qq * 4 + j;
                h[s] = fmaf(EXP2F(dl * a2[s]), h[s], du * Bv[j]);
                y = fmaf(h[s], Cv[j], y);
            }
        }
        *op = fmaf(Dd, xv, y);
        op += DINNER;
        dl = dln; xv = xvn;
    }
    {
        float du = dl * xv;
        float y = 0.f;
        const floatx4* Pq = (const floatx4*)&BC[(LCHUNK - 1) * 32];
#pragma unroll
        for (int qq = 0; qq < 4; ++qq) {
            floatx4 Bv = Pq[qq];
            floatx4 Cv = Pq[qq + 4];
#pragma unroll
            for (int j = 0; j < 4; ++j) {
                int s = qq * 4 + j;
                h[s] = fmaf(EXP2F(dl * a2[s]), h[s], du * Bv[j]);
                y = fmaf(h[s], Cv[j], y);
            }
        }
        *op = fmaf(Dd, xv, y);
    }
}

extern "C" void kernel_launch(void* const* d_in, const int* in_sizes, int n_in,
                              void* d_out, int out_size, void* d_ws, size_t ws_size,
                              hipStream_t stream) {
    const float* x    = (const float*)d_in[0];
    const float* Wdbc = (const float*)d_in[1];
    const float* bdbc = (const float*)d_in[2];
    const float* Wdt  = (const float*)d_in[3];
    const float* bdt  = (const float*)d_in[4];
    const float* Alog = (const float*)d_in[5];
    const float* Dp   = (const float*)d_in[6];
    float* out = (float*)d_out;

    char* w = (char*)d_ws;
    __hip_bfloat16* wdbch = (__hip_bfloat16*)w;  w += (size_t)NDBC * FEAT * 2;
    __hip_bfloat16* wdbcl = (__hip_bfloat16*)w;  w += (size_t)NDBC * FEAT * 2;
    __hip_bfloat16* wdth = (__hip_bfloat16*)w;   w += (size_t)DINNER * DTRANK * 2;
    __hip_bfloat16* wdtl = (__hip_bfloat16*)w;   w += (size_t)DINNER * DTRANK * 2;
    float* partial = (float*)w;                  w += (size_t)KSPLIT * BL * NDBC * 4;   // 21 MB
    float* dbcBC = (float*)w;                    w += (size_t)BL * 32 * 4;              // 0.5 MB
    __hip_bfloat16* dhi = (__hip_bfloat16*)w;    w += (size_t)BL * DTRANK * 2;          // 1 MB
    __hip_bfloat16* dlo = (__hip_bfloat16*)w;    w += (size_t)BL * DTRANK * 2;          // 1 MB
    float* delta = (float*)w;                    w += (size_t)BL * DINNER * 4;          // 33.6 MB
    float* A2T = (float*)w;                      w += (size_t)DSTATE * DINNER * 4;      // 0.13 MB
    float* hA = (float*)w;                       w += (size_t)BATCH * NCHUNK * DINNER * DSTATE * 4; // 16.8 MB
    float* sumd = (float*)w;                     w += (size_t)BATCH * NCHUNK * DINNER * 4;          // 1 MB

    hipLaunchKernelGGL(split_bf16, dim3(NDBC * FEAT / 8 / 256), dim3(256), 0, stream,
                       Wdbc, wdbch, wdbcl, NDBC * FEAT / 8);
    hipLaunchKernelGGL(split_bf16, dim3(DINNER * DTRANK / 8 / 256), dim3(256), 0, stream,
                       Wdt, wdth, wdtl, DINNER * DTRANK / 8);
    hipLaunchKernelGGL(prep_a2, dim3((DSTATE * DINNER) / 256), dim3(256), 0, stream, Alog, A2T);
    hipLaunchKernelGGL(gemm_dbc, dim3(BL / 64, KSPLIT), dim3(256), 0, stream,
                       x, wdbch, wdbcl, partial);
    hipLaunchKernelGGL(finalize_dbc, dim3(BL * 40 / 256), dim3(256), 0, stream,
                       partial, bdbc, dbcBC, dhi, dlo);
    hipLaunchKernelGGL(gemm_dt, dim3(BL / 128, DINNER / 64), dim3(256), 0, stream,
                       dhi, dlo, wdth, wdtl, bdt, delta);
    hipLaunchKernelGGL(scan_partial, dim3((BATCH * NCHUNK * DINNER) / 256), dim3(256), 0, stream,
                       delta, x, dbcBC, A2T, hA, sumd);
    hipLaunchKernelGGL(scan_combine, dim3((BATCH * DINNER * DSTATE) / 256), dim3(256), 0, stream,
                       hA, sumd, A2T);
    hipLaunchKernelGGL(scan_final, dim3((BATCH * NCHUNK * DINNER) / 256), dim3(256), 0, stream,
                       delta, x, dbcBC, A2T, hA, Dp, out);
}

// Round 7
// 210.514 us; speedup vs baseline: 1.5524x; 1.0054x over previous
//
#include <hip/hip_runtime.h>
#include <hip/hip_bf16.h>
#include <math.h>

#define BATCH  2
#define LSEQ   2048
#define FEAT   2048
#define DINNER 2048
#define DSTATE 16
#define DTRANK 128
#define NDBC   160             // DT_RANK + 2*D_STATE
#define NCHUNK 64
#define LCHUNK (LSEQ / NCHUNK) // 32
#define BL     (BATCH * LSEQ)  // 4096
#define KSPLIT 4
#define KCH    (FEAT / KSPLIT) // 512
#define KSUB   64
#define BSTRIDE 72             // LDS row stride (bf16): conflict-safe b128

typedef __attribute__((ext_vector_type(8))) short bf16x8;
typedef __attribute__((ext_vector_type(4))) short bf16x4;
typedef __attribute__((ext_vector_type(4))) float floatx4;

#if __has_builtin(__builtin_amdgcn_exp2f)
#define EXP2F(x) __builtin_amdgcn_exp2f(x)
#else
#define EXP2F(x) exp2f(x)
#endif
#if __has_builtin(__builtin_amdgcn_logf)
#define LOG2F(x) __builtin_amdgcn_logf(x)
#else
#define LOG2F(x) __log2f(x)
#endif

// softplus via HW transcendentals: max(v,0) + ln2*log2(1+2^(-|v|*log2e))
__device__ inline float softplus_fast(float v) {
    float e = EXP2F(-fabsf(v) * 1.4426950408889634f);
    return fmaxf(v, 0.f) + 0.6931471805599453f * LOG2F(1.f + e);
}

__device__ inline void split8(floatx4 a0, floatx4 a1, bf16x8* h, bf16x8* l) {
    union { bf16x8 v; __hip_bfloat16 e[8]; } H, L;
    float v[8] = {a0[0], a0[1], a0[2], a0[3], a1[0], a1[1], a1[2], a1[3]};
#pragma unroll
    for (int i = 0; i < 8; ++i) {
        H.e[i] = __float2bfloat16(v[i]);
        L.e[i] = __float2bfloat16(v[i] - __bfloat162float(H.e[i]));
    }
    *h = H.v; *l = L.v;
}

__device__ inline void split_store8(const float* __restrict__ src, int t,
                                    __hip_bfloat16* __restrict__ hi,
                                    __hip_bfloat16* __restrict__ lo) {
    const floatx4* s4 = (const floatx4*)(src) + t * 2;
    bf16x8 h, l;
    split8(s4[0], s4[1], &h, &l);
    ((bf16x8*)hi)[t] = h;
    ((bf16x8*)lo)[t] = l;
}

// ---------------- merged prep: W splits + A2T, one launch ----------------
// blocks [0,160): Wdbc split; [160,288): Wdt split; [288,416): A2T
__global__ __launch_bounds__(256) void prep_all(
    const float* __restrict__ Wdbc, const float* __restrict__ Wdt,
    const float* __restrict__ Alog,
    __hip_bfloat16* __restrict__ wdbch, __hip_bfloat16* __restrict__ wdbcl,
    __hip_bfloat16* __restrict__ wdth, __hip_bfloat16* __restrict__ wdtl,
    float* __restrict__ A2T)
{
    int blk = blockIdx.x;
    if (blk < 160) {
        split_store8(Wdbc, blk * 256 + threadIdx.x, wdbch, wdbcl);
    } else if (blk < 288) {
        split_store8(Wdt, (blk - 160) * 256 + threadIdx.x, wdth, wdtl);
    } else {
        int tid = (blk - 288) * 256 + threadIdx.x;   // 32768
        int s = tid >> 11;
        int d = tid & (DINNER - 1);
        A2T[s * DINNER + d] = -__expf(Alog[d * DSTATE + s]) * 1.4426950408889634f;
    }
}

// ---------------- GEMM1 split-K: partial[ks] = x(chunk) @ W_dbc(chunk)^T ----------------
__global__ __launch_bounds__(256) void gemm_dbc(
    const float* __restrict__ x,
    const __hip_bfloat16* __restrict__ wh, const __hip_bfloat16* __restrict__ wl,
    float* __restrict__ partial)
{
    __shared__ union {
        struct { __hip_bfloat16 Bh[NDBC * BSTRIDE]; __hip_bfloat16 Bl[NDBC * BSTRIDE]; } s;
        float tile[64 * 164];   // 41984 B
    } sm;
    int mt = blockIdx.x, ks = blockIdx.y;
    int t = threadIdx.x;
    int wave = t >> 6, lane = t & 63, lm = lane & 15, q = lane >> 4;
    int m0 = mt * 64;
    int k0 = ks * KCH;
    const float* xrow = x + (size_t)(m0 + wave * 16 + lm) * FEAT;
    floatx4 acc[10];
#pragma unroll
    for (int i = 0; i < 10; ++i) acc[i] = (floatx4){0.f, 0.f, 0.f, 0.f};
    int sr = t >> 3, scb = t & 7;
    for (int kc = 0; kc < KCH; kc += KSUB) {
#pragma unroll
        for (int r = sr; r < NDBC; r += 32) {
            size_t g = (size_t)r * FEAT + k0 + kc + scb * 8;
            *(bf16x8*)&sm.s.Bh[r * BSTRIDE + scb * 8] = *(const bf16x8*)&wh[g];
            *(bf16x8*)&sm.s.Bl[r * BSTRIDE + scb * 8] = *(const bf16x8*)&wl[g];
        }
        __syncthreads();
#pragma unroll
        for (int kk = 0; kk < KSUB; kk += 32) {
            int col = k0 + kc + kk + q * 8;
            floatx4 a0 = *(const floatx4*)(xrow + col);
            floatx4 a1 = *(const floatx4*)(xrow + col + 4);
            bf16x8 ah, al;
            split8(a0, a1, &ah, &al);
#pragma unroll
            for (int nt = 0; nt < 10; ++nt) {
                int boff = (nt * 16 + lm) * BSTRIDE + kk + q * 8;
                bf16x8 bh = *(const bf16x8*)&sm.s.Bh[boff];
                bf16x8 bl = *(const bf16x8*)&sm.s.Bl[boff];
                acc[nt] = __builtin_amdgcn_mfma_f32_16x16x32_bf16(ah, bh, acc[nt], 0, 0, 0);
                acc[nt] = __builtin_amdgcn_mfma_f32_16x16x32_bf16(ah, bl, acc[nt], 0, 0, 0);
                acc[nt] = __builtin_amdgcn_mfma_f32_16x16x32_bf16(al, bh, acc[nt], 0, 0, 0);
            }
        }
        __syncthreads();
    }
    // LDS epilogue -> coalesced float4 stores
#pragma unroll
    for (int nt = 0; nt < 10; ++nt)
#pragma unroll
        for (int i = 0; i < 4; ++i)
            sm.tile[(wave * 16 + q * 4 + i) * 164 + nt * 16 + lm] = acc[nt][i];
    __syncthreads();
#pragma unroll
    for (int it = 0; it < 10; ++it) {
        int idx = it * 256 + t;
        int row = idx / 40, cq = (idx - row * 40) * 4;
        floatx4 v = *(const floatx4*)&sm.tile[row * 164 + cq];
        *(floatx4*)&partial[((size_t)ks * BL + m0 + row) * NDBC + cq] = v;
    }
}

// ---------------- finalize: sum K-partials + bias -> dbcBC fp32 + delta_lo hi/lo ----------------
__global__ __launch_bounds__(256) void finalize_dbc(
    const float* __restrict__ partial, const float* __restrict__ bias,
    float* __restrict__ dbcBC, __hip_bfloat16* __restrict__ dhi, __hip_bfloat16* __restrict__ dlo)
{
    int tid = blockIdx.x * 256 + threadIdx.x;  // 163840
    int m = tid / 40, c4 = tid - m * 40;
    int n = c4 * 4;
    floatx4 s = *(const floatx4*)(bias + n);
#pragma unroll
    for (int ks = 0; ks < KSPLIT; ++ks) {
        floatx4 p = *(const floatx4*)(partial + ((size_t)ks * BL + m) * NDBC + n);
        s = s + p;
    }
    if (c4 < 32) {
        union { bf16x4 v; __hip_bfloat16 e[4]; } H, L;
#pragma unroll
        for (int i = 0; i < 4; ++i) {
            H.e[i] = __float2bfloat16(s[i]);
            L.e[i] = __float2bfloat16(s[i] - __bfloat162float(H.e[i]));
        }
        *(bf16x4*)(dhi + (size_t)m * DTRANK + n) = H.v;
        *(bf16x4*)(dlo + (size_t)m * DTRANK + n) = L.v;
    } else {
        *(floatx4*)(dbcBC + (size_t)m * 32 + (n - 128)) = s;
    }
}

// ---------------- GEMM2: delta = softplus(delta_lo @ W_dt^T + b_dt) ----------------
__global__ __launch_bounds__(256) void gemm_dt(
    const __hip_bfloat16* __restrict__ dhi, const __hip_bfloat16* __restrict__ dlo,
    const __hip_bfloat16* __restrict__ wh, const __hip_bfloat16* __restrict__ wl,
    const float* __restrict__ bdt, float* __restrict__ delta)
{
    __shared__ float tile[128 * 68];   // 34816 B
    int mt = blockIdx.x, ntb = blockIdx.y;   // (32, 32)
    int t = threadIdx.x, wave = t >> 6, lane = t & 63, lm = lane & 15, q = lane >> 4;
    int m0 = mt * 128 + wave * 32;
    int n0 = ntb * 64;
    bf16x8 AH[2][4], AL[2][4];
#pragma unroll
    for (int sub = 0; sub < 2; ++sub) {
        const __hip_bfloat16* ah = dhi + (size_t)(m0 + sub * 16 + lm) * DTRANK + q * 8;
        const __hip_bfloat16* al = dlo + (size_t)(m0 + sub * 16 + lm) * DTRANK + q * 8;
#pragma unroll
        for (int kp = 0; kp < 4; ++kp) {
            AH[sub][kp] = *(const bf16x8*)(ah + kp * 32);
            AL[sub][kp] = *(const bf16x8*)(al + kp * 32);
        }
    }
    floatx4 acc[4][2];
#pragma unroll
    for (int i = 0; i < 4; ++i)
#pragma unroll
        for (int j = 0; j < 2; ++j) acc[i][j] = (floatx4){0.f, 0.f, 0.f, 0.f};
#pragma unroll
    for (int nt = 0; nt < 4; ++nt) {
        const __hip_bfloat16* bh = wh + (size_t)(n0 + nt * 16 + lm) * DTRANK + q * 8;
        const __hip_bfloat16* blp = wl + (size_t)(n0 + nt * 16 + lm) * DTRANK + q * 8;
#pragma unroll
        for (int kp = 0; kp < 4; ++kp) {
            bf16x8 bhv = *(const bf16x8*)(bh + kp * 32);
            bf16x8 blv = *(const bf16x8*)(blp + kp * 32);
#pragma unroll
            for (int sub = 0; sub < 2; ++sub) {
                acc[nt][sub] = __builtin_amdgcn_mfma_f32_16x16x32_bf16(AH[sub][kp], bhv, acc[nt][sub], 0, 0, 0);
                acc[nt][sub] = __builtin_amdgcn_mfma_f32_16x16x32_bf16(AH[sub][kp], blv, acc[nt][sub], 0, 0, 0);
                acc[nt][sub] = __builtin_amdgcn_mfma_f32_16x16x32_bf16(AL[sub][kp], bhv, acc[nt][sub], 0, 0, 0);
            }
        }
    }
    // fast softplus + LDS epilogue -> coalesced stores
    int wrow = wave * 32;
#pragma unroll
    for (int nt = 0; nt < 4; ++nt) {
        float bias = bdt[n0 + nt * 16 + lm];
#pragma unroll
        for (int sub = 0; sub < 2; ++sub)
#pragma unroll
            for (int i = 0; i < 4; ++i) {
                float v = acc[nt][sub][i] + bias;
                tile[(wrow + sub * 16 + q * 4 + i) * 68 + nt * 16 + lm] = softplus_fast(v);
            }
    }
    __syncthreads();
#pragma unroll
    for (int it = 0; it < 8; ++it) {
        int idx = it * 256 + t;
        int row = idx >> 4, cq = (idx & 15) * 4;
        floatx4 v = *(const floatx4*)&tile[row * 68 + cq];
        *(floatx4*)&delta[(size_t)(mt * 128 + row) * DINNER + n0 + cq] = v;
    }
}

// ---------------- Pass A: chunk-local scan; B in LDS; prefetch depth 2 ----------------
__global__ __launch_bounds__(256) void scan_partial(
    const float* __restrict__ delta, const float* __restrict__ x,
    const float* __restrict__ dbcBC, const float* __restrict__ A2T,
    float* __restrict__ hA, float* __restrict__ sumd)
{
    __shared__ float BC[LCHUNK * 32];  // 4 KB
    int t = threadIdx.x;
    int gtid = blockIdx.x * 256 + t;
    int d = gtid & (DINNER - 1);
    int c = (gtid >> 11) & (NCHUNK - 1);
    int b = gtid >> 17;
    {
        int row = t >> 3, cq = (t & 7) * 4;
        *(floatx4*)&BC[row * 32 + cq] =
            *(const floatx4*)&dbcBC[(size_t)(b * LSEQ + c * LCHUNK + row) * 32 + cq];
    }
    float a2[DSTATE], h[DSTATE];
#pragma unroll
    for (int s = 0; s < DSTATE; ++s) { a2[s] = A2T[s * DINNER + d]; h[s] = 0.f; }
    __syncthreads();
    int base = (b * LSEQ + c * LCHUNK) * DINNER + d;
    const float* dp = delta + base;
    const float* xp = x + base;
    float sd = 0.f;
    auto step = [&](int i, float dl, float xv) {
        float du = dl * xv;
        sd += dl;
        const floatx4* Bq = (const floatx4*)&BC[i * 32];
#pragma unroll
        for (int qq = 0; qq < 4; ++qq) {
            floatx4 Bv = Bq[qq];
#pragma unroll
            for (int j = 0; j < 4; ++j) {
                int s = qq * 4 + j;
                h[s] = fmaf(EXP2F(dl * a2[s]), h[s], du * Bv[j]);
            }
        }
    };
    float dlA = dp[0], xvA = xp[0];
    float dlB = dp[DINNER], xvB = xp[DINNER];
    for (int i = 0; i < LCHUNK - 2; ++i) {
        float dlC = dp[(i + 2) * DINNER];
        float xvC = xp[(i + 2) * DINNER];
        step(i, dlA, xvA);
        dlA = dlB; xvA = xvB; dlB = dlC; xvB = xvC;
    }
    step(LCHUNK - 2, dlA, xvA);
    step(LCHUNK - 1, dlB, xvB);
    // hA layout [b][c][q][d][4] -> coalesced float4
    size_t hbase = ((size_t)((b * NCHUNK + c) * 4) * DINNER + d) * 4;
#pragma unroll
    for (int qq = 0; qq < 4; ++qq) {
        floatx4 v = {h[qq * 4], h[qq * 4 + 1], h[qq * 4 + 2], h[qq * 4 + 3]};
        *(floatx4*)&hA[hbase + (size_t)qq * DINNER * 4] = v;
    }
    sumd[(size_t)(b * NCHUNK + c) * DINNER + d] = sd;
}

// ---------------- Pass B: exclusive combine, 16-wide batched loads ----------------
__global__ __launch_bounds__(256) void scan_combine(
    float* __restrict__ hA, const float* __restrict__ sumd, const float* __restrict__ A2T)
{
    int tid = blockIdx.x * 256 + threadIdx.x;  // 65536
    int s = tid & 15;
    int d = (tid >> 4) & (DINNER - 1);
    int b = tid >> 15;
    float a2s = A2T[s * DINNER + d];
    int q = s >> 2, e = s & 3;
    size_t hoff = ((size_t)(b * NCHUNK * 4 + q) * DINNER + d) * 4 + e;  // c=0
    size_t soff = (size_t)(b * NCHUNK) * DINNER + d;
    const size_t hstep = (size_t)16 * DINNER;  // per-c stride in floats
    float hin = 0.f;
#pragma unroll
    for (int g = 0; g < NCHUNK / 16; ++g) {
        float sdv[16], hv[16];
#pragma unroll
        for (int k = 0; k < 16; ++k) {
            int cc = g * 16 + k;
            sdv[k] = sumd[soff + (size_t)cc * DINNER];
            hv[k] = hA[hoff + (size_t)cc * hstep];
        }
#pragma unroll
        for (int k = 0; k < 16; ++k) {
            int cc = g * 16 + k;
            hA[hoff + (size_t)cc * hstep] = hin;
            hin = EXP2F(a2s * sdv[k]) * hin + hv[k];
        }
    }
}

// ---------------- Pass C: re-scan from h_in, emit y; B/C in LDS; prefetch depth 2 ----
__global__ __launch_bounds__(256) void scan_final(
    const float* __restrict__ delta, const float* __restrict__ x,
    const float* __restrict__ dbcBC, const float* __restrict__ A2T,
    const float* __restrict__ hin, const float* __restrict__ Dp,
    float* __restrict__ out)
{
    __shared__ float BC[LCHUNK * 32];  // 4 KB
    int t = threadIdx.x;
    int gtid = blockIdx.x * 256 + t;
    int d = gtid & (DINNER - 1);
    int c = (gtid >> 11) & (NCHUNK - 1);
    int b = gtid >> 17;
    {
        int row = t >> 3, cq = (t & 7) * 4;
        *(floatx4*)&BC[row * 32 + cq] =
            *(const floatx4*)&dbcBC[(size_t)(b * LSEQ + c * LCHUNK + row) * 32 + cq];
    }
    float a2[DSTATE], h[DSTATE];
    size_t hbase = ((size_t)((b * NCHUNK + c) * 4) * DINNER + d) * 4;
#pragma unroll
    for (int qq = 0; qq < 4; ++qq) {
        floatx4 v = *(const floatx4*)&hin[hbase + (size_t)qq * DINNER * 4];
#pragma unroll
        for (int j = 0; j < 4; ++j) h[qq * 4 + j] = v[j];
    }
#pragma unroll
    for (int s = 0; s < DSTATE; ++s) a2[s] = A2T[s * DINNER + d];
    float Dd = Dp[d];
    __syncthreads();
    int base = (b * LSEQ + c * LCHUNK) * DINNER + d;
    const float* dp = delta + base;
    const float* xp = x + base;
    float* op = out + base;
    auto step = [&](int i, float dl, float xv) {
        float du = dl * xv;
        float y = 0.f;
        const floatx4* Pq = (const floatx4*)&BC[i * 32];
#pragma unroll
        for (int qq = 0; qq < 4; ++qq) {
            floatx4 Bv = Pq[qq];
            floatx4 Cv = Pq[qq + 4];
#pragma unroll
            for (int j = 0; j < 4; ++j) {
                int s = qq * 4 + j;
                h[s] = fmaf(EXP2F(dl * a2[s]), h[s], du * Bv[j]);
                y = fmaf(h[s], Cv[j], y);
            }
        }
        op[i * DINNER] = fmaf(Dd, xv, y);
    };
    float dlA = dp[0], xvA = xp[0];
    float dlB = dp[DINNER], xvB = xp[DINNER];
    for (int i = 0; i < LCHUNK - 2; ++i) {
        float dlC = dp[(i + 2) * DINNER];
        float xvC = xp[(i + 2) * DINNER];
        step(i, dlA, xvA);
        dlA = dlB; xvA = xvB; dlB = dlC; xvB = xvC;
    }
    step(LCHUNK - 2, dlA, xvA);
    step(LCHUNK - 1, dlB, xvB);
}

extern "C" void kernel_launch(void* const* d_in, const int* in_sizes, int n_in,
                              void* d_out, int out_size, void* d_ws, size_t ws_size,
                              hipStream_t stream) {
    const float* x    = (const float*)d_in[0];
    const float* Wdbc = (const float*)d_in[1];
    const float* bdbc = (const float*)d_in[2];
    const float* Wdt  = (const float*)d_in[3];
    const float* bdt  = (const float*)d_in[4];
    const float* Alog = (const float*)d_in[5];
    const float* Dp   = (const float*)d_in[6];
    float* out = (float*)d_out;

    char* w = (char*)d_ws;
    __hip_bfloat16* wdbch = (__hip_bfloat16*)w;  w += (size_t)NDBC * FEAT * 2;
    __hip_bfloat16* wdbcl = (__hip_bfloat16*)w;  w += (size_t)NDBC * FEAT * 2;
    __hip_bfloat16* wdth = (__hip_bfloat16*)w;   w += (size_t)DINNER * DTRANK * 2;
    __hip_bfloat16* wdtl = (__hip_bfloat16*)w;   w += (size_t)DINNER * DTRANK * 2;
    float* partial = (float*)w;                  w += (size_t)KSPLIT * BL * NDBC * 4;   // 10.5 MB
    float* dbcBC = (float*)w;                    w += (size_t)BL * 32 * 4;              // 0.5 MB
    __hip_bfloat16* dhi = (__hip_bfloat16*)w;    w += (size_t)BL * DTRANK * 2;          // 1 MB
    __hip_bfloat16* dlo = (__hip_bfloat16*)w;    w += (size_t)BL * DTRANK * 2;          // 1 MB
    float* delta = (float*)w;                    w += (size_t)BL * DINNER * 4;          // 33.6 MB
    float* A2T = (float*)w;                      w += (size_t)DSTATE * DINNER * 4;      // 0.13 MB
    float* hA = (float*)w;                       w += (size_t)BATCH * NCHUNK * DINNER * DSTATE * 4; // 16.8 MB
    float* sumd = (float*)w;                     w += (size_t)BATCH * NCHUNK * DINNER * 4;          // 1 MB

    hipLaunchKernelGGL(prep_all, dim3(416), dim3(256), 0, stream,
                       Wdbc, Wdt, Alog, wdbch, wdbcl, wdth, wdtl, A2T);
    hipLaunchKernelGGL(gemm_dbc, dim3(BL / 64, KSPLIT), dim3(256), 0, stream,
                       x, wdbch, wdbcl, partial);
    hipLaunchKernelGGL(finalize_dbc, dim3(BL * 40 / 256), dim3(256), 0, stream,
                       partial, bdbc, dbcBC, dhi, dlo);
    hipLaunchKernelGGL(gemm_dt, dim3(BL / 128, DINNER / 64), dim3(256), 0, stream,
                       dhi, dlo, wdth, wdtl, bdt, delta);
    hipLaunchKernelGGL(scan_partial, dim3((BATCH * NCHUNK * DINNER) / 256), dim3(256), 0, stream,
                       delta, x, dbcBC, A2T, hA, sumd);
    hipLaunchKernelGGL(scan_combine, dim3((BATCH * DINNER * DSTATE) / 256), dim3(256), 0, stream,
                       hA, sumd, A2T);
    hipLaunchKernelGGL(scan_final, dim3((BATCH * NCHUNK * DINNER) / 256), dim3(256), 0, stream,
                       delta, x, dbcBC, A2T, hA, Dp, out);
}

// Round 8
// 206.197 us; speedup vs baseline: 1.5849x; 1.0209x over previous
//
#include <hip/hip_runtime.h>
#include <hip/hip_bf16.h>
#include <math.h>

#define BATCH  2
#define LSEQ   2048
#define FEAT   2048
#define DINNER 2048
#define DSTATE 16
#define DTRANK 128
#define NDBC   160             // DT_RANK + 2*D_STATE
#define NCHUNK 64
#define LCHUNK (LSEQ / NCHUNK) // 32
#define BL     (BATCH * LSEQ)  // 4096
#define KSPLIT 8
#define KCH    (FEAT / KSPLIT) // 256
#define KSUB   64
#define BSTRIDE 72             // LDS row stride (bf16): conflict-safe b128
#define GRP    8               // scan prefetch group size

typedef __attribute__((ext_vector_type(8))) short bf16x8;
typedef __attribute__((ext_vector_type(4))) short bf16x4;
typedef __attribute__((ext_vector_type(4))) float floatx4;

#if __has_builtin(__builtin_amdgcn_exp2f)
#define EXP2F(x) __builtin_amdgcn_exp2f(x)
#else
#define EXP2F(x) exp2f(x)
#endif
#if __has_builtin(__builtin_amdgcn_logf)
#define LOG2F(x) __builtin_amdgcn_logf(x)
#else
#define LOG2F(x) __log2f(x)
#endif

// softplus via HW transcendentals: max(v,0) + ln2*log2(1+2^(-|v|*log2e))
__device__ inline float softplus_fast(float v) {
    float e = EXP2F(-fabsf(v) * 1.4426950408889634f);
    return fmaxf(v, 0.f) + 0.6931471805599453f * LOG2F(1.f + e);
}

__device__ inline void split8(floatx4 a0, floatx4 a1, bf16x8* h, bf16x8* l) {
    union { bf16x8 v; __hip_bfloat16 e[8]; } H, L;
    float v[8] = {a0[0], a0[1], a0[2], a0[3], a1[0], a1[1], a1[2], a1[3]};
#pragma unroll
    for (int i = 0; i < 8; ++i) {
        H.e[i] = __float2bfloat16(v[i]);
        L.e[i] = __float2bfloat16(v[i] - __bfloat162float(H.e[i]));
    }
    *h = H.v; *l = L.v;
}

__device__ inline void split_store8(const float* __restrict__ src, int t,
                                    __hip_bfloat16* __restrict__ hi,
                                    __hip_bfloat16* __restrict__ lo) {
    const floatx4* s4 = (const floatx4*)(src) + t * 2;
    bf16x8 h, l;
    split8(s4[0], s4[1], &h, &l);
    ((bf16x8*)hi)[t] = h;
    ((bf16x8*)lo)[t] = l;
}

// ---------------- merged prep: W splits + A2T, one launch ----------------
__global__ __launch_bounds__(256) void prep_all(
    const float* __restrict__ Wdbc, const float* __restrict__ Wdt,
    const float* __restrict__ Alog,
    __hip_bfloat16* __restrict__ wdbch, __hip_bfloat16* __restrict__ wdbcl,
    __hip_bfloat16* __restrict__ wdth, __hip_bfloat16* __restrict__ wdtl,
    float* __restrict__ A2T)
{
    int blk = blockIdx.x;
    if (blk < 160) {
        split_store8(Wdbc, blk * 256 + threadIdx.x, wdbch, wdbcl);
    } else if (blk < 288) {
        split_store8(Wdt, (blk - 160) * 256 + threadIdx.x, wdth, wdtl);
    } else {
        int tid = (blk - 288) * 256 + threadIdx.x;   // 32768
        int s = tid >> 11;
        int d = tid & (DINNER - 1);
        A2T[s * DINNER + d] = -__expf(Alog[d * DSTATE + s]) * 1.4426950408889634f;
    }
}

// ---------------- GEMM1 split-K: partial[ks] = x(chunk) @ W_dbc(chunk)^T ----------------
__global__ __launch_bounds__(256) void gemm_dbc(
    const float* __restrict__ x,
    const __hip_bfloat16* __restrict__ wh, const __hip_bfloat16* __restrict__ wl,
    float* __restrict__ partial)
{
    __shared__ union {
        struct { __hip_bfloat16 Bh[NDBC * BSTRIDE]; __hip_bfloat16 Bl[NDBC * BSTRIDE]; } s;
        float tile[64 * 164];   // 41984 B
    } sm;
    int mt = blockIdx.x, ks = blockIdx.y;
    int t = threadIdx.x;
    int wave = t >> 6, lane = t & 63, lm = lane & 15, q = lane >> 4;
    int m0 = mt * 64;
    int k0 = ks * KCH;
    const float* xrow = x + (size_t)(m0 + wave * 16 + lm) * FEAT;
    floatx4 acc[10];
#pragma unroll
    for (int i = 0; i < 10; ++i) acc[i] = (floatx4){0.f, 0.f, 0.f, 0.f};
    int sr = t >> 3, scb = t & 7;
    for (int kc = 0; kc < KCH; kc += KSUB) {
#pragma unroll
        for (int r = sr; r < NDBC; r += 32) {
            size_t g = (size_t)r * FEAT + k0 + kc + scb * 8;
            *(bf16x8*)&sm.s.Bh[r * BSTRIDE + scb * 8] = *(const bf16x8*)&wh[g];
            *(bf16x8*)&sm.s.Bl[r * BSTRIDE + scb * 8] = *(const bf16x8*)&wl[g];
        }
        __syncthreads();
#pragma unroll
        for (int kk = 0; kk < KSUB; kk += 32) {
            int col = k0 + kc + kk + q * 8;
            floatx4 a0 = *(const floatx4*)(xrow + col);
            floatx4 a1 = *(const floatx4*)(xrow + col + 4);
            bf16x8 ah, al;
            split8(a0, a1, &ah, &al);
#pragma unroll
            for (int nt = 0; nt < 10; ++nt) {
                int boff = (nt * 16 + lm) * BSTRIDE + kk + q * 8;
                bf16x8 bh = *(const bf16x8*)&sm.s.Bh[boff];
                bf16x8 bl = *(const bf16x8*)&sm.s.Bl[boff];
                acc[nt] = __builtin_amdgcn_mfma_f32_16x16x32_bf16(ah, bh, acc[nt], 0, 0, 0);
                acc[nt] = __builtin_amdgcn_mfma_f32_16x16x32_bf16(ah, bl, acc[nt], 0, 0, 0);
                acc[nt] = __builtin_amdgcn_mfma_f32_16x16x32_bf16(al, bh, acc[nt], 0, 0, 0);
            }
        }
        __syncthreads();
    }
    // LDS epilogue -> coalesced float4 stores
#pragma unroll
    for (int nt = 0; nt < 10; ++nt)
#pragma unroll
        for (int i = 0; i < 4; ++i)
            sm.tile[(wave * 16 + q * 4 + i) * 164 + nt * 16 + lm] = acc[nt][i];
    __syncthreads();
#pragma unroll
    for (int it = 0; it < 10; ++it) {
        int idx = it * 256 + t;
        int row = idx / 40, cq = (idx - row * 40) * 4;
        floatx4 v = *(const floatx4*)&sm.tile[row * 164 + cq];
        *(floatx4*)&partial[((size_t)ks * BL + m0 + row) * NDBC + cq] = v;
    }
}

// ---------------- finalize: sum K-partials + bias -> dbcBC fp32 + delta_lo hi/lo ----------------
__global__ __launch_bounds__(256) void finalize_dbc(
    const float* __restrict__ partial, const float* __restrict__ bias,
    float* __restrict__ dbcBC, __hip_bfloat16* __restrict__ dhi, __hip_bfloat16* __restrict__ dlo)
{
    int tid = blockIdx.x * 256 + threadIdx.x;  // 163840
    int m = tid / 40, c4 = tid - m * 40;
    int n = c4 * 4;
    floatx4 s = *(const floatx4*)(bias + n);
#pragma unroll
    for (int ks = 0; ks < KSPLIT; ++ks) {
        floatx4 p = *(const floatx4*)(partial + ((size_t)ks * BL + m) * NDBC + n);
        s = s + p;
    }
    if (c4 < 32) {
        union { bf16x4 v; __hip_bfloat16 e[4]; } H, L;
#pragma unroll
        for (int i = 0; i < 4; ++i) {
            H.e[i] = __float2bfloat16(s[i]);
            L.e[i] = __float2bfloat16(s[i] - __bfloat162float(H.e[i]));
        }
        *(bf16x4*)(dhi + (size_t)m * DTRANK + n) = H.v;
        *(bf16x4*)(dlo + (size_t)m * DTRANK + n) = L.v;
    } else {
        *(floatx4*)(dbcBC + (size_t)m * 32 + (n - 128)) = s;
    }
}

// ---------------- GEMM2: delta = softplus(delta_lo @ W_dt^T + b_dt) ----------------
__global__ __launch_bounds__(256) void gemm_dt(
    const __hip_bfloat16* __restrict__ dhi, const __hip_bfloat16* __restrict__ dlo,
    const __hip_bfloat16* __restrict__ wh, const __hip_bfloat16* __restrict__ wl,
    const float* __restrict__ bdt, float* __restrict__ delta)
{
    __shared__ float tile[128 * 68];   // 34816 B
    int mt = blockIdx.x, ntb = blockIdx.y;   // (32, 32)
    int t = threadIdx.x, wave = t >> 6, lane = t & 63, lm = lane & 15, q = lane >> 4;
    int m0 = mt * 128 + wave * 32;
    int n0 = ntb * 64;
    bf16x8 AH[2][4], AL[2][4];
#pragma unroll
    for (int sub = 0; sub < 2; ++sub) {
        const __hip_bfloat16* ah = dhi + (size_t)(m0 + sub * 16 + lm) * DTRANK + q * 8;
        const __hip_bfloat16* al = dlo + (size_t)(m0 + sub * 16 + lm) * DTRANK + q * 8;
#pragma unroll
        for (int kp = 0; kp < 4; ++kp) {
            AH[sub][kp] = *(const bf16x8*)(ah + kp * 32);
            AL[sub][kp] = *(const bf16x8*)(al + kp * 32);
        }
    }
    floatx4 acc[4][2];
#pragma unroll
    for (int i = 0; i < 4; ++i)
#pragma unroll
        for (int j = 0; j < 2; ++j) acc[i][j] = (floatx4){0.f, 0.f, 0.f, 0.f};
#pragma unroll
    for (int nt = 0; nt < 4; ++nt) {
        const __hip_bfloat16* bh = wh + (size_t)(n0 + nt * 16 + lm) * DTRANK + q * 8;
        const __hip_bfloat16* blp = wl + (size_t)(n0 + nt * 16 + lm) * DTRANK + q * 8;
#pragma unroll
        for (int kp = 0; kp < 4; ++kp) {
            bf16x8 bhv = *(const bf16x8*)(bh + kp * 32);
            bf16x8 blv = *(const bf16x8*)(blp + kp * 32);
#pragma unroll
            for (int sub = 0; sub < 2; ++sub) {
                acc[nt][sub] = __builtin_amdgcn_mfma_f32_16x16x32_bf16(AH[sub][kp], bhv, acc[nt][sub], 0, 0, 0);
                acc[nt][sub] = __builtin_amdgcn_mfma_f32_16x16x32_bf16(AH[sub][kp], blv, acc[nt][sub], 0, 0, 0);
                acc[nt][sub] = __builtin_amdgcn_mfma_f32_16x16x32_bf16(AL[sub][kp], bhv, acc[nt][sub], 0, 0, 0);
            }
        }
    }
    // fast softplus + LDS epilogue -> coalesced stores
    int wrow = wave * 32;
#pragma unroll
    for (int nt = 0; nt < 4; ++nt) {
        float bias = bdt[n0 + nt * 16 + lm];
#pragma unroll
        for (int sub = 0; sub < 2; ++sub)
#pragma unroll
            for (int i = 0; i < 4; ++i) {
                float v = acc[nt][sub][i] + bias;
                tile[(wrow + sub * 16 + q * 4 + i) * 68 + nt * 16 + lm] = softplus_fast(v);
            }
    }
    __syncthreads();
#pragma unroll
    for (int it = 0; it < 8; ++it) {
        int idx = it * 256 + t;
        int row = idx >> 4, cq = (idx & 15) * 4;
        floatx4 v = *(const floatx4*)&tile[row * 68 + cq];
        *(floatx4*)&delta[(size_t)(mt * 128 + row) * DINNER + n0 + cq] = v;
    }
}

// ---------------- Pass A: chunk-local scan; B in LDS; group-8 batched prefetch ----------------
__global__ __launch_bounds__(256) void scan_partial(
    const float* __restrict__ delta, const float* __restrict__ x,
    const float* __restrict__ dbcBC, const float* __restrict__ A2T,
    float* __restrict__ hA, float* __restrict__ sumd)
{
    __shared__ float BC[LCHUNK * 32];  // 4 KB
    int t = threadIdx.x;
    int gtid = blockIdx.x * 256 + t;
    int d = gtid & (DINNER - 1);
    int c = (gtid >> 11) & (NCHUNK - 1);
    int b = gtid >> 17;
    {
        int row = t >> 3, cq = (t & 7) * 4;
        *(floatx4*)&BC[row * 32 + cq] =
            *(const floatx4*)&dbcBC[(size_t)(b * LSEQ + c * LCHUNK + row) * 32 + cq];
    }
    float a2[DSTATE], h[DSTATE];
#pragma unroll
    for (int s = 0; s < DSTATE; ++s) { a2[s] = A2T[s * DINNER + d]; h[s] = 0.f; }
    __syncthreads();
    int base = (b * LSEQ + c * LCHUNK) * DINNER + d;
    const float* dp = delta + base;
    const float* xp = x + base;
    float sd = 0.f;
    float dlb[2][GRP], xvb[2][GRP];
#pragma unroll
    for (int j = 0; j < GRP; ++j) { dlb[0][j] = dp[j * DINNER]; xvb[0][j] = xp[j * DINNER]; }
#pragma unroll
    for (int g = 0; g < LCHUNK / GRP; ++g) {
        int p = g & 1;
        if (g + 1 < LCHUNK / GRP) {
#pragma unroll
            for (int j = 0; j < GRP; ++j) {
                dlb[1 - p][j] = dp[((g + 1) * GRP + j) * DINNER];
                xvb[1 - p][j] = xp[((g + 1) * GRP + j) * DINNER];
            }
        }
#pragma unroll
        for (int j = 0; j < GRP; ++j) {
            float dl = dlb[p][j], xv = xvb[p][j];
            float du = dl * xv;
            sd += dl;
            const floatx4* Bq = (const floatx4*)&BC[(g * GRP + j) * 32];
#pragma unroll
            for (int qq = 0; qq < 4; ++qq) {
                floatx4 Bv = Bq[qq];
#pragma unroll
                for (int jj = 0; jj < 4; ++jj) {
                    int s = qq * 4 + jj;
                    h[s] = fmaf(EXP2F(dl * a2[s]), h[s], du * Bv[jj]);
                }
            }
        }
    }
    // hA layout [b][c][q][d][4] -> coalesced float4
    size_t hbase = ((size_t)((b * NCHUNK + c) * 4) * DINNER + d) * 4;
#pragma unroll
    for (int qq = 0; qq < 4; ++qq) {
        floatx4 v = {h[qq * 4], h[qq * 4 + 1], h[qq * 4 + 2], h[qq * 4 + 3]};
        *(floatx4*)&hA[hbase + (size_t)qq * DINNER * 4] = v;
    }
    sumd[(size_t)(b * NCHUNK + c) * DINNER + d] = sd;
}

// ---------------- Pass B: exclusive combine, 16-wide batched loads ----------------
__global__ __launch_bounds__(256) void scan_combine(
    float* __restrict__ hA, const float* __restrict__ sumd, const float* __restrict__ A2T)
{
    int tid = blockIdx.x * 256 + threadIdx.x;  // 65536
    int s = tid & 15;
    int d = (tid >> 4) & (DINNER - 1);
    int b = tid >> 15;
    float a2s = A2T[s * DINNER + d];
    int q = s >> 2, e = s & 3;
    size_t hoff = ((size_t)(b * NCHUNK * 4 + q) * DINNER + d) * 4 + e;  // c=0
    size_t soff = (size_t)(b * NCHUNK) * DINNER + d;
    const size_t hstep = (size_t)16 * DINNER;  // per-c stride in floats
    float hin = 0.f;
#pragma unroll
    for (int g = 0; g < NCHUNK / 16; ++g) {
        float sdv[16], hv[16];
#pragma unroll
        for (int k = 0; k < 16; ++k) {
            int cc = g * 16 + k;
            sdv[k] = sumd[soff + (size_t)cc * DINNER];
            hv[k] = hA[hoff + (size_t)cc * hstep];
        }
#pragma unroll
        for (int k = 0; k < 16; ++k) {
            int cc = g * 16 + k;
            hA[hoff + (size_t)cc * hstep] = hin;
            hin = EXP2F(a2s * sdv[k]) * hin + hv[k];
        }
    }
}

// ---------------- Pass C: re-scan from h_in, emit y; B/C in LDS; group-8 prefetch ----
__global__ __launch_bounds__(256) void scan_final(
    const float* __restrict__ delta, const float* __restrict__ x,
    const float* __restrict__ dbcBC, const float* __restrict__ A2T,
    const float* __restrict__ hin, const float* __restrict__ Dp,
    float* __restrict__ out)
{
    __shared__ float BC[LCHUNK * 32];  // 4 KB
    int t = threadIdx.x;
    int gtid = blockIdx.x * 256 + t;
    int d = gtid & (DINNER - 1);
    int c = (gtid >> 11) & (NCHUNK - 1);
    int b = gtid >> 17;
    {
        int row = t >> 3, cq = (t & 7) * 4;
        *(floatx4*)&BC[row * 32 + cq] =
            *(const floatx4*)&dbcBC[(size_t)(b * LSEQ + c * LCHUNK + row) * 32 + cq];
    }
    float a2[DSTATE], h[DSTATE];
    size_t hbase = ((size_t)((b * NCHUNK + c) * 4) * DINNER + d) * 4;
#pragma unroll
    for (int qq = 0; qq < 4; ++qq) {
        floatx4 v = *(const floatx4*)&hin[hbase + (size_t)qq * DINNER * 4];
#pragma unroll
        for (int j = 0; j < 4; ++j) h[qq * 4 + j] = v[j];
    }
#pragma unroll
    for (int s = 0; s < DSTATE; ++s) a2[s] = A2T[s * DINNER + d];
    float Dd = Dp[d];
    __syncthreads();
    int base = (b * LSEQ + c * LCHUNK) * DINNER + d;
    const float* dp = delta + base;
    const float* xp = x + base;
    float* op = out + base;
    float dlb[2][GRP], xvb[2][GRP];
#pragma unroll
    for (int j = 0; j < GRP; ++j) { dlb[0][j] = dp[j * DINNER]; xvb[0][j] = xp[j * DINNER]; }
#pragma unroll
    for (int g = 0; g < LCHUNK / GRP; ++g) {
        int p = g & 1;
        if (g + 1 < LCHUNK / GRP) {
#pragma unroll
            for (int j = 0; j < GRP; ++j) {
                dlb[1 - p][j] = dp[((g + 1) * GRP + j) * DINNER];
                xvb[1 - p][j] = xp[((g + 1) * GRP + j) * DINNER];
            }
        }
#pragma unroll
        for (int j = 0; j < GRP; ++j) {
            float dl = dlb[p][j], xv = xvb[p][j];
            int i = g * GRP + j;
            float du = dl * xv;
            float y = 0.f;
            const floatx4* Pq = (const floatx4*)&BC[i * 32];
#pragma unroll
            for (int qq = 0; qq < 4; ++qq) {
                floatx4 Bv = Pq[qq];
                floatx4 Cv = Pq[qq + 4];
#pragma unroll
                for (int jj = 0; jj < 4; ++jj) {
                    int s = qq * 4 + jj;
                    h[s] = fmaf(EXP2F(dl * a2[s]), h[s], du * Bv[jj]);
                    y = fmaf(h[s], Cv[jj], y);
                }
            }
            op[i * DINNER] = fmaf(Dd, xv, y);
        }
    }
}

extern "C" void kernel_launch(void* const* d_in, const int* in_sizes, int n_in,
                              void* d_out, int out_size, void* d_ws, size_t ws_size,
                              hipStream_t stream) {
    const float* x    = (const float*)d_in[0];
    const float* Wdbc = (const float*)d_in[1];
    const float* bdbc = (const float*)d_in[2];
    const float* Wdt  = (const float*)d_in[3];
    const float* bdt  = (const float*)d_in[4];
    const float* Alog = (const float*)d_in[5];
    const float* Dp   = (const float*)d_in[6];
    float* out = (float*)d_out;

    char* w = (char*)d_ws;
    __hip_bfloat16* wdbch = (__hip_bfloat16*)w;  w += (size_t)NDBC * FEAT * 2;
    __hip_bfloat16* wdbcl = (__hip_bfloat16*)w;  w += (size_t)NDBC * FEAT * 2;
    __hip_bfloat16* wdth = (__hip_bfloat16*)w;   w += (size_t)DINNER * DTRANK * 2;
    __hip_bfloat16* wdtl = (__hip_bfloat16*)w;   w += (size_t)DINNER * DTRANK * 2;
    float* partial = (float*)w;                  w += (size_t)KSPLIT * BL * NDBC * 4;   // 21 MB
    float* dbcBC = (float*)w;                    w += (size_t)BL * 32 * 4;              // 0.5 MB
    __hip_bfloat16* dhi = (__hip_bfloat16*)w;    w += (size_t)BL * DTRANK * 2;          // 1 MB
    __hip_bfloat16* dlo = (__hip_bfloat16*)w;    w += (size_t)BL * DTRANK * 2;          // 1 MB
    float* delta = (float*)w;                    w += (size_t)BL * DINNER * 4;          // 33.6 MB
    float* A2T = (float*)w;                      w += (size_t)DSTATE * DINNER * 4;      // 0.13 MB
    float* hA = (float*)w;                       w += (size_t)BATCH * NCHUNK * DINNER * DSTATE * 4; // 16.8 MB
    float* sumd = (float*)w;                     w += (size_t)BATCH * NCHUNK * DINNER * 4;          // 1 MB

    hipLaunchKernelGGL(prep_all, dim3(416), dim3(256), 0, stream,
                       Wdbc, Wdt, Alog, wdbch, wdbcl, wdth, wdtl, A2T);
    hipLaunchKernelGGL(gemm_dbc, dim3(BL / 64, KSPLIT), dim3(256), 0, stream,
                       x, wdbch, wdbcl, partial);
    hipLaunchKernelGGL(finalize_dbc, dim3(BL * 40 / 256), dim3(256), 0, stream,
                       partial, bdbc, dbcBC, dhi, dlo);
    hipLaunchKernelGGL(gemm_dt, dim3(BL / 128, DINNER / 64), dim3(256), 0, stream,
                       dhi, dlo, wdth, wdtl, bdt, delta);
    hipLaunchKernelGGL(scan_partial, dim3((BATCH * NCHUNK * DINNER) / 256), dim3(256), 0, stream,
                       delta, x, dbcBC, A2T, hA, sumd);
    hipLaunchKernelGGL(scan_combine, dim3((BATCH * DINNER * DSTATE) / 256), dim3(256), 0, stream,
                       hA, sumd, A2T);
    hipLaunchKernelGGL(scan_final, dim3((BATCH * NCHUNK * DINNER) / 256), dim3(256), 0, stream,
                       delta, x, dbcBC, A2T, hA, Dp, out);
}